// Round 2
// baseline (390.509 us; speedup 1.0000x reference)
//
#include <hip/hip_runtime.h>
#include <stdint.h>

typedef unsigned int u32;
typedef unsigned short u16;
typedef __bf16 bf16x8 __attribute__((ext_vector_type(8)));
typedef float floatx16 __attribute__((ext_vector_type(16)));
typedef u32 u32x4 __attribute__((ext_vector_type(4)));
typedef float floatx4 __attribute__((ext_vector_type(4)));

__device__ __forceinline__ u16 f2b(float f) {
    u32 u = __builtin_bit_cast(u32, f);
    u32 r = u + 0x7FFFu + ((u >> 16) & 1u);
    return (u16)(r >> 16);
}
__device__ __forceinline__ float lo2f(u32 u) { return __builtin_bit_cast(float, u << 16); }
__device__ __forceinline__ float hi2f(u32 u) { return __builtin_bit_cast(float, u & 0xFFFF0000u); }

// ---------------- wave-uniform self-detection ----------------
__device__ __forceinline__ void self_detect(const int* ei, const u32* xw, int& is64, int& isbf) {
    int lane = threadIdx.x & 63;
    int v = ei ? ei[2 * lane + 1] : 0;
    unsigned long long b1 = __ballot(v == 0);
    u32 w = xw ? xw[lane] : 0;
    u32 e = (w >> 7) & 0xFF;
    int plaus = (e == 0) || (e >= 90 && e <= 140);
    unsigned long long b2 = __ballot(plaus);
    is64 = (b1 == ~0ULL) ? 1 : 0;
    isbf = (b2 == ~0ULL) ? 1 : 0;
}

__device__ __forceinline__ int load_id(const int* __restrict__ ei, int is64, size_t pos, int N) {
    int v = is64 ? ei[2 * pos] : ei[pos];
    unsigned u = (unsigned)v;
    if (u >= (unsigned)N) u = 0;  // clamp: never OOB
    return (int)u;
}

__device__ __forceinline__ float load_f(const void* __restrict__ p, int isbf, size_t i) {
    if (isbf) {
        u16 s = ((const u16*)p)[i];
        return __builtin_bit_cast(float, ((u32)s) << 16);
    }
    return ((const float*)p)[i];
}

// ---------------- merged front: convert_x + wprep + smalls + bucket_scatter ----------------
// (unchanged, proven)
#define CH 4096
#define CAPB 3072

__global__ __launch_bounds__(1024) void front_kernel(
    const void* __restrict__ xraw, const int* __restrict__ ei, int E, int N, int cvb,
    u32* __restrict__ xb, int* __restrict__ gcur, u32* __restrict__ csrbkt,
    const void* Wl1, const void* Wr1, const void* Wl2, const void* Wr2,
    const void* Wl3, const void* Wr3, const void* b1, const void* b2,
    const void* b3, const void* Wo, const void* bo,
    u16* __restrict__ Wcp, float* __restrict__ smalls) {
    __shared__ int lhist[1024], loff[1024], lcur[1024], gofs[1024], wsum[16];
    __shared__ u32 ebuf[CH];
    __shared__ u16 ebkt[CH];
    int blk = blockIdx.x;
    int t = threadIdx.x;

    if (blk < cvb) {
        int is64, isbf;
        self_detect(nullptr, (const u32*)xraw, is64, isbf);
        int i = blk * 1024 + t;
        int count4 = N * 16;
        if (i >= count4) return;
        if (isbf) {
            ((u32x4*)xb)[i] = ((const u32x4*)xraw)[i];
        } else {
            const floatx4* f4 = (const floatx4*)xraw;
            floatx4 f0 = f4[2 * i], f1 = f4[2 * i + 1];
            u32x4 o;
            o.x = (u32)f2b(f0.x) | ((u32)f2b(f0.y) << 16);
            o.y = (u32)f2b(f0.z) | ((u32)f2b(f0.w) << 16);
            o.z = (u32)f2b(f1.x) | ((u32)f2b(f1.y) << 16);
            o.w = (u32)f2b(f1.z) | ((u32)f2b(f1.w) << 16);
            ((u32x4*)xb)[i] = o;
        }
        return;
    }
    if (blk < cvb + 12) {
        int is64, isbf;
        self_detect(nullptr, (const u32*)xraw, is64, isbf);
        int tg = (blk - cvb) * 1024 + t;  // 0..12287
        int l = tg >> 12;
        int tt = tg & 4095;
        const void* Wl = (l == 0) ? Wl1 : (l == 1) ? Wl2 : Wl3;
        const void* Wr = (l == 0) ? Wr1 : (l == 1) ? Wr2 : Wr3;
        u16* Wout = Wcp + (size_t)l * 32768;
        int lane = tt & 63;
        int jt = (tt >> 6) & 3;
        int s = tt >> 8;
        int n = lane & 31;
        int q = lane >> 5;
        int j = jt * 32 + n;
#pragma unroll
        for (int jj = 0; jj < 8; ++jj) {
            int k = s * 16 + q * 8 + jj;
            float v = (k < 128) ? load_f(Wl, isbf, (size_t)j * 128 + k)
                                : load_f(Wr, isbf, (size_t)j * 128 + (k - 128));
            Wout[tt * 8 + jj] = f2b(v);
        }
        return;
    }
    if (blk == cvb + 12) {
        int is64, isbf;
        self_detect(nullptr, (const u32*)xraw, is64, isbf);
        if (t < 642) {
            float v;
            if (t < 128) v = load_f(b1, isbf, t);
            else if (t < 256) v = load_f(b2, isbf, t - 128);
            else if (t < 384) v = load_f(b3, isbf, t - 256);
            else if (t < 640) v = load_f(Wo, isbf, t - 384);
            else v = load_f(bo, isbf, t - 640);
            smalls[t] = v;
        }
        return;
    }

    // ---- scatter role ----
    int is64, isbf;
    self_detect(ei, nullptr, is64, isbf);
    int cbase = (blk - (cvb + 13)) * CH;
    int cn = E - cbase;
    if (cn > CH) cn = CH;
    lhist[t] = 0;
    __syncthreads();
    int mysrc[4], myb[4], mydl[4];
#pragma unroll
    for (int k = 0; k < 4; ++k) {
        int i = t + k * 1024;
        myb[k] = -1;
        if (i < cn) {
            int e = cbase + i;
            int s = load_id(ei, is64, (size_t)e, N);
            int d = load_id(ei, is64, (size_t)E + e, N);
            mysrc[k] = s;
            mydl[k] = d & 255;
            myb[k] = d >> 8;
            atomicAdd(&lhist[myb[k]], 1);
        }
    }
    __syncthreads();
    int lane = t & 63, wid = t >> 6;
    int v = lhist[t];
    int inc = v;
#pragma unroll
    for (int off = 1; off < 64; off <<= 1) {
        int o = __shfl_up(inc, off);
        if (lane >= off) inc += o;
    }
    if (lane == 63) wsum[wid] = inc;
    __syncthreads();
    int wpre = 0;
    for (int w = 0; w < wid; ++w) wpre += wsum[w];
    int excl = wpre + inc - v;
    loff[t] = excl;
    lcur[t] = excl;
    if (v > 0) gofs[t] = atomicAdd(&gcur[t], v);
    __syncthreads();
#pragma unroll
    for (int k = 0; k < 4; ++k) {
        if (myb[k] >= 0) {
            int pos = atomicAdd(&lcur[myb[k]], 1);
            ebuf[pos] = (u32)mysrc[k] | ((u32)mydl[k] << 24);
            ebkt[pos] = (u16)myb[k];
        }
    }
    __syncthreads();
#pragma unroll
    for (int k = 0; k < 4; ++k) {
        int i = t + k * 1024;
        if (i < cn) {
            int bb = ebkt[i];
            int local = gofs[bb] + (i - loff[bb]);
            if (local < CAPB) csrbkt[(size_t)bb * CAPB + local] = ebuf[i];
        }
    }
}

// one block per bucket: counting-sort by dst-low, compact into csr via gtot cursor
__global__ void csr_build_kernel(const u32* __restrict__ csrbkt, const int* __restrict__ gcur,
                                 int N, int* __restrict__ gtot,
                                 int* __restrict__ offs, int* __restrict__ cnt,
                                 int* __restrict__ csr) {
    __shared__ int lh[256], lcur[256], wsum[4];
    __shared__ int sbase;
    __shared__ u32 sbuf[CAPB];
    int t = threadIdx.x;  // 256
    int b = blockIdx.x;
    int cb = gcur[b];
    if (cb > CAPB) cb = CAPB;
    const u32* bsrc = csrbkt + (size_t)b * CAPB;
    int d0 = b << 8;
    lh[t] = 0;
    __syncthreads();
    for (int i = t; i < cb; i += 256) atomicAdd(&lh[bsrc[i] >> 24], 1);
    __syncthreads();
    int lane = t & 63, wid = t >> 6;
    int v = lh[t];
    int inc = v;
#pragma unroll
    for (int off = 1; off < 64; off <<= 1) {
        int o = __shfl_up(inc, off);
        if (lane >= off) inc += o;
    }
    if (lane == 63) wsum[wid] = inc;
    __syncthreads();
    int wpre = 0;
    for (int w = 0; w < wid; ++w) wpre += wsum[w];
    int excl = wpre + inc - v;
    lcur[t] = excl;
    if (t == 0) sbase = atomicAdd(gtot, cb);
    __syncthreads();
    int base = sbase;
    int d = d0 + t;
    if (d < N) {
        offs[d] = base + excl;
        cnt[d] = v;
    }
    for (int i = t; i < cb; i += 256) {
        u32 e = bsrc[i];
        int pos = atomicAdd(&lcur[e >> 24], 1);
        sbuf[pos] = e & 0xFFFFFFu;
    }
    __syncthreads();
    for (int i = t; i < cb; i += 256) csr[base + i] = (int)sbuf[i];
}

// ---------------- fused layer: gather-aggregate -> LDS -> dual-GEMM ----------------
// block = 256 threads (4 waves), owns 128 nodes. Wave w aggregates nodes
// [nbase+w*32, +32) -- exactly the rows its MFMA A-fragments need -- into an
// LDS tile [128][68] u32 (pad 68 -> 4-way b128 conflict max). No barrier:
// each wave writes and reads only its own 32 LDS rows.
//
// Gather (per wave): 8 groups x 4 nodes; 32 lanes (li) cover a 256 B row via
// uint2, halves take even/odd edges. VALU-lean inner loop:
//  - csr over-allocated by CAPB+pad => padded loads need no clamp
//  - invalid slots gather row N (memset to 0) => no data masking, 1 cndmask
//  - u32 byte offsets (N*256 < 2^31) => v_lshl_add_u32 addressing
// Reads xcur (prev layer, read-only), writes xnxt => no in-place race.

#define LSTRIDE 68

__global__ __launch_bounds__(256) void layer_kernel(
    const u32* __restrict__ xcur, u32* __restrict__ xnxt,
    const int* __restrict__ offs, const int* __restrict__ cnt,
    const int* __restrict__ csr,
    const u16* __restrict__ Wcp, const float* __restrict__ biasf,
    int N, int relu, const float* __restrict__ headw,
    const u32* __restrict__ xw, void* __restrict__ outp) {
    __shared__ u32 ldsA[128 * LSTRIDE];
    int tid = threadIdx.x;
    int w = tid >> 6;
    int lane = tid & 63;
    int li = lane & 31;
    int half = lane >> 5;
    int nbase = blockIdx.x * 128;
    int wrow0 = w * 32;

    // ---- gather phase ----
    u32 li8 = (u32)li * 8u;
    const char* fb = (const char*)xcur;
    for (int g = 0; g < 8; ++g) {
        int nd0 = nbase + wrow0 + g * 4;
        int st[4], ct[4];
#pragma unroll
        for (int j = 0; j < 4; ++j) {
            int nd = nd0 + j;
            st[j] = (nd < N) ? offs[nd] : 0;
            ct[j] = (nd < N) ? cnt[nd] : 0;
        }
        float acc[4][4];
#pragma unroll
        for (int j = 0; j < 4; ++j)
#pragma unroll
            for (int f = 0; f < 4; ++f) acc[j][f] = 0.f;

        int maxct = max(max(ct[0], ct[1]), max(ct[2], ct[3]));
        for (int pos = 0; pos < maxct; pos += 8) {
            u32 ax[4][4], ay[4][4];
#pragma unroll
            for (int j = 0; j < 4; ++j) {
                int rem = ct[j] - pos;
                int cb = st[j] + pos + half;
#pragma unroll
                for (int k = 0; k < 4; ++k) {
                    u32 sv = (u32)csr[cb + 2 * k];          // padded reads safe (over-alloc)
                    u32 se = ((2 * k + half) < rem) ? sv : (u32)N;  // zero row
                    u32 off = (se << 8) + li8;
                    uint2 u = *reinterpret_cast<const uint2*>(fb + off);
                    ax[j][k] = u.x;
                    ay[j][k] = u.y;
                }
            }
#pragma unroll
            for (int j = 0; j < 4; ++j) {
#pragma unroll
                for (int k = 0; k < 4; ++k) {
                    acc[j][0] += lo2f(ax[j][k]);
                    acc[j][1] += hi2f(ax[j][k]);
                    acc[j][2] += lo2f(ay[j][k]);
                    acc[j][3] += hi2f(ay[j][k]);
                }
            }
        }
        // combine halves (disjoint edge subsets)
#pragma unroll
        for (int j = 0; j < 4; ++j)
#pragma unroll
            for (int f = 0; f < 4; ++f) acc[j][f] += __shfl_xor(acc[j][f], 32);

        if (half == 0) {
#pragma unroll
            for (int j = 0; j < 4; ++j) {
                float sc = 1.0f / (float)(ct[j] > 1 ? ct[j] : 1);
                u32 o0 = (u32)f2b(acc[j][0] * sc) | ((u32)f2b(acc[j][1] * sc) << 16);
                u32 o1 = (u32)f2b(acc[j][2] * sc) | ((u32)f2b(acc[j][3] * sc) << 16);
                int row = wrow0 + g * 4 + j;
                u32* lp = &ldsA[row * LSTRIDE + li * 2];
                lp[0] = o0;
                lp[1] = o1;
            }
        }
    }
    // no __syncthreads: each wave reads only its own LDS rows (in-wave lgkm order)

    // ---- MFMA phase (proven dual-GEMM) ----
    int n = li;
    int q = half;
    int rowl = wrow0 + n;
    int node = nbase + rowl;
    int nodeC = (node < N) ? node : (N - 1);
    const u32* fRow = xcur + (size_t)nodeC * 64 + q * 4;
    const u32* aRowL = &ldsA[rowl * LSTRIDE + q * 4];

    floatx16 acc0 = 0.0f, acc1 = 0.0f, acc2 = 0.0f, acc3 = 0.0f;

#pragma unroll
    for (int s = 0; s < 8; ++s) {
        bf16x8 a = *reinterpret_cast<const bf16x8*>(aRowL + s * 8);
        const u16* bp = Wcp + (size_t)((s * 4) * 64 + lane) * 8;
        bf16x8 b0 = *reinterpret_cast<const bf16x8*>(bp);
        bf16x8 b1 = *reinterpret_cast<const bf16x8*>(bp + 64 * 8);
        bf16x8 b2 = *reinterpret_cast<const bf16x8*>(bp + 2 * 64 * 8);
        bf16x8 b3 = *reinterpret_cast<const bf16x8*>(bp + 3 * 64 * 8);
        acc0 = __builtin_amdgcn_mfma_f32_32x32x16_bf16(a, b0, acc0, 0, 0, 0);
        acc1 = __builtin_amdgcn_mfma_f32_32x32x16_bf16(a, b1, acc1, 0, 0, 0);
        acc2 = __builtin_amdgcn_mfma_f32_32x32x16_bf16(a, b2, acc2, 0, 0, 0);
        acc3 = __builtin_amdgcn_mfma_f32_32x32x16_bf16(a, b3, acc3, 0, 0, 0);
    }
#pragma unroll
    for (int s = 8; s < 16; ++s) {
        bf16x8 a = *reinterpret_cast<const bf16x8*>(fRow + (size_t)(s - 8) * 8);
        const u16* bp = Wcp + (size_t)((s * 4) * 64 + lane) * 8;
        bf16x8 b0 = *reinterpret_cast<const bf16x8*>(bp);
        bf16x8 b1 = *reinterpret_cast<const bf16x8*>(bp + 64 * 8);
        bf16x8 b2 = *reinterpret_cast<const bf16x8*>(bp + 2 * 64 * 8);
        bf16x8 b3 = *reinterpret_cast<const bf16x8*>(bp + 3 * 64 * 8);
        acc0 = __builtin_amdgcn_mfma_f32_32x32x16_bf16(a, b0, acc0, 0, 0, 0);
        acc1 = __builtin_amdgcn_mfma_f32_32x32x16_bf16(a, b1, acc1, 0, 0, 0);
        acc2 = __builtin_amdgcn_mfma_f32_32x32x16_bf16(a, b2, acc2, 0, 0, 0);
        acc3 = __builtin_amdgcn_mfma_f32_32x32x16_bf16(a, b3, acc3, 0, 0, 0);
    }

    int mbase = nbase + w * 32;
    floatx16 accs[4] = {acc0, acc1, acc2, acc3};
    // C/D: col=lane&31, row=(r&3)+8*(r>>2)+4*(lane>>5)  [verified m74/m101]

    if (outp == nullptr) {
#pragma unroll
        for (int jt = 0; jt < 4; ++jt) {
            int j0 = jt * 32 + n;
            float bf = biasf[j0];
#pragma unroll
            for (int r = 0; r < 16; ++r) {
                int row = (r & 3) + 8 * (r >> 2) + 4 * q;
                int nodeS = mbase + row;
                if (nodeS < N) {
                    float v = accs[jt][r] + bf;
                    if (relu) v = fmaxf(v, 0.0f);
                    u16* dst16 = (u16*)&xnxt[(size_t)nodeS * 64];
                    dst16[j0] = f2b(v);
                }
            }
        }
    } else {
        // fused head: out[node] = (h·Wo0 + bo0, h·Wo1 + bo1); h = acc + bl3
        int is64, isbf;
        self_detect(nullptr, xw, is64, isbf);  // full wave active here
#pragma unroll
        for (int r = 0; r < 16; ++r) {
            float p0 = 0.f, p1 = 0.f;
#pragma unroll
            for (int jt = 0; jt < 4; ++jt) {
                int j = jt * 32 + n;
                float v = accs[jt][r] + biasf[j];
                p0 += v * headw[j];
                p1 += v * headw[128 + j];
            }
#pragma unroll
            for (int off = 16; off > 0; off >>= 1) {
                p0 += __shfl_xor(p0, off);
                p1 += __shfl_xor(p1, off);
            }
            if (n == 0) {
                int row = (r & 3) + 8 * (r >> 2) + 4 * q;
                int nodeS = mbase + row;
                if (nodeS < N) {
                    float o0 = p0 + headw[256];  // bo0
                    float o1 = p1 + headw[257];  // bo1
                    if (isbf)
                        ((u32*)outp)[nodeS] = (u32)f2b(o0) | ((u32)f2b(o1) << 16);
                    else
                        ((float2*)outp)[nodeS] = make_float2(o0, o1);
                }
            }
        }
    }
}

extern "C" void kernel_launch(void* const* d_in, const int* in_sizes, int n_in,
                              void* d_out, int out_size, void* d_ws, size_t ws_size,
                              hipStream_t stream) {
    const int N = in_sizes[0] / 128;
    const int E = in_sizes[1] / 2;

    const void* x = d_in[0];
    const int* ei = (const int*)d_in[1];
    const void* Wl[3] = {d_in[2], d_in[5], d_in[8]};
    const void* bl[3] = {d_in[3], d_in[6], d_in[9]};
    const void* Wr[3] = {d_in[4], d_in[7], d_in[10]};
    const void* Wo = d_in[11];
    const void* bo = d_in[12];

    // workspace bump allocator (256B aligned)
    char* p = (char*)d_ws;
    auto alloc = [&](size_t bytes) -> char* {
        char* r = p;
        p += (bytes + 255) & ~(size_t)255;
        return r;
    };
    int* offs = (int*)alloc((size_t)N * 4);
    int* cnt = (int*)alloc((size_t)N * 4);
    float* smalls = (float*)alloc(642 * 4);
    int* gcur = (int*)alloc(1025 * 4);  // [1024] = gtot
    int* csr = (int*)alloc(((size_t)E + CAPB + 64) * 4);  // over-alloc: padded reads safe
    u16* Wcp = (u16*)alloc((size_t)3 * 4096 * 8 * 2);
    u32* x0 = (u32*)alloc((size_t)(N + 1) * 64 * 4);  // +1: zero row for masked gathers
    u32* x1 = (u32*)alloc((size_t)(N + 1) * 64 * 4);  // aliased as csrbkt during build
    u32* csrbkt = x1;                                  // dead until layers start
    int* gtot = gcur + 1024;
    (void)ws_size;

    const int NB = (N + 255) / 256;          // buckets
    const int cvb = (N * 16 + 1023) / 1024;  // convert blocks (1024 thr)
    const int sb = (E + CH - 1) / CH;        // scatter blocks
    const int gb = (N + 127) / 128;          // layer blocks (tiles)

    hipMemsetAsync(gcur, 0, 1025 * 4, stream);
    front_kernel<<<cvb + 13 + sb, 1024, 0, stream>>>(
        x, ei, E, N, cvb, x0, gcur, csrbkt,
        Wl[0], Wr[0], Wl[1], Wr[1], Wl[2], Wr[2],
        bl[0], bl[1], bl[2], Wo, bo, Wcp, smalls);
    csr_build_kernel<<<NB, 256, 0, stream>>>(csrbkt, gcur, N, gtot, offs, cnt, csr);
    // zero rows (row N) for masked-slot gathers; x1's row is dead csrbkt space by now
    hipMemsetAsync(x0 + (size_t)N * 64, 0, 256, stream);
    hipMemsetAsync(x1 + (size_t)N * 64, 0, 256, stream);

    // layer 1: x0 -> x1
    layer_kernel<<<gb, 256, 0, stream>>>(x0, x1, offs, cnt, csr, Wcp, smalls, N, 1,
                                         nullptr, nullptr, nullptr);
    // layer 2: x1 -> x0
    layer_kernel<<<gb, 256, 0, stream>>>(x1, x0, offs, cnt, csr, Wcp + 32768, smalls + 128, N, 1,
                                         nullptr, nullptr, nullptr);
    // layer 3 + fused head: x0 -> d_out
    layer_kernel<<<gb, 256, 0, stream>>>(x0, x1, offs, cnt, csr, Wcp + 65536, smalls + 256, N, 0,
                                         smalls + 384, (const u32*)x, d_out);
}

// Round 3
// 346.931 us; speedup vs baseline: 1.1256x; 1.1256x over previous
//
#include <hip/hip_runtime.h>
#include <stdint.h>

typedef unsigned int u32;
typedef unsigned short u16;
typedef __bf16 bf16x8 __attribute__((ext_vector_type(8)));
typedef float floatx16 __attribute__((ext_vector_type(16)));
typedef u32 u32x4 __attribute__((ext_vector_type(4)));
typedef float floatx4 __attribute__((ext_vector_type(4)));

__device__ __forceinline__ u16 f2b(float f) {
    u32 u = __builtin_bit_cast(u32, f);
    u32 r = u + 0x7FFFu + ((u >> 16) & 1u);
    return (u16)(r >> 16);
}
__device__ __forceinline__ float lo2f(u32 u) { return __builtin_bit_cast(float, u << 16); }
__device__ __forceinline__ float hi2f(u32 u) { return __builtin_bit_cast(float, u & 0xFFFF0000u); }

// ---------------- wave-uniform self-detection ----------------
__device__ __forceinline__ void self_detect(const int* ei, const u32* xw, int& is64, int& isbf) {
    int lane = threadIdx.x & 63;
    int v = ei ? ei[2 * lane + 1] : 0;
    unsigned long long b1 = __ballot(v == 0);
    u32 w = xw ? xw[lane] : 0;
    u32 e = (w >> 7) & 0xFF;
    int plaus = (e == 0) || (e >= 90 && e <= 140);
    unsigned long long b2 = __ballot(plaus);
    is64 = (b1 == ~0ULL) ? 1 : 0;
    isbf = (b2 == ~0ULL) ? 1 : 0;
}

__device__ __forceinline__ int load_id(const int* __restrict__ ei, int is64, size_t pos, int N) {
    int v = is64 ? ei[2 * pos] : ei[pos];
    unsigned u = (unsigned)v;
    if (u >= (unsigned)N) u = 0;  // clamp: never OOB
    return (int)u;
}

__device__ __forceinline__ float load_f(const void* __restrict__ p, int isbf, size_t i) {
    if (isbf) {
        u16 s = ((const u16*)p)[i];
        return __builtin_bit_cast(float, ((u32)s) << 16);
    }
    return ((const float*)p)[i];
}

// ---------------- merged front: convert_x + wprep + smalls + bucket_scatter ----------------
// (proven; smalls block additionally zeroes feature row N for masked gathers)
#define CH 4096
#define CAPB 3072

__global__ __launch_bounds__(1024) void front_kernel(
    const void* __restrict__ xraw, const int* __restrict__ ei, int E, int N, int cvb,
    u32* __restrict__ xb, int* __restrict__ gcur, u32* __restrict__ csrbkt,
    const void* Wl1, const void* Wr1, const void* Wl2, const void* Wr2,
    const void* Wl3, const void* Wr3, const void* b1, const void* b2,
    const void* b3, const void* Wo, const void* bo,
    u16* __restrict__ Wcp, float* __restrict__ smalls) {
    __shared__ int lhist[1024], loff[1024], lcur[1024], gofs[1024], wsum[16];
    __shared__ u32 ebuf[CH];
    __shared__ u16 ebkt[CH];
    int blk = blockIdx.x;
    int t = threadIdx.x;

    if (blk < cvb) {
        int is64, isbf;
        self_detect(nullptr, (const u32*)xraw, is64, isbf);
        int i = blk * 1024 + t;
        int count4 = N * 16;
        if (i >= count4) return;
        if (isbf) {
            ((u32x4*)xb)[i] = ((const u32x4*)xraw)[i];
        } else {
            const floatx4* f4 = (const floatx4*)xraw;
            floatx4 f0 = f4[2 * i], f1 = f4[2 * i + 1];
            u32x4 o;
            o.x = (u32)f2b(f0.x) | ((u32)f2b(f0.y) << 16);
            o.y = (u32)f2b(f0.z) | ((u32)f2b(f0.w) << 16);
            o.z = (u32)f2b(f1.x) | ((u32)f2b(f1.y) << 16);
            o.w = (u32)f2b(f1.z) | ((u32)f2b(f1.w) << 16);
            ((u32x4*)xb)[i] = o;
        }
        return;
    }
    if (blk < cvb + 12) {
        int is64, isbf;
        self_detect(nullptr, (const u32*)xraw, is64, isbf);
        int tg = (blk - cvb) * 1024 + t;  // 0..12287
        int l = tg >> 12;
        int tt = tg & 4095;
        const void* Wl = (l == 0) ? Wl1 : (l == 1) ? Wl2 : Wl3;
        const void* Wr = (l == 0) ? Wr1 : (l == 1) ? Wr2 : Wr3;
        u16* Wout = Wcp + (size_t)l * 32768;
        int lane = tt & 63;
        int jt = (tt >> 6) & 3;
        int s = tt >> 8;
        int n = lane & 31;
        int q = lane >> 5;
        int j = jt * 32 + n;
#pragma unroll
        for (int jj = 0; jj < 8; ++jj) {
            int k = s * 16 + q * 8 + jj;
            float v = (k < 128) ? load_f(Wl, isbf, (size_t)j * 128 + k)
                                : load_f(Wr, isbf, (size_t)j * 128 + (k - 128));
            Wout[tt * 8 + jj] = f2b(v);
        }
        return;
    }
    if (blk == cvb + 12) {
        int is64, isbf;
        self_detect(nullptr, (const u32*)xraw, is64, isbf);
        if (t < 642) {
            float v;
            if (t < 128) v = load_f(b1, isbf, t);
            else if (t < 256) v = load_f(b2, isbf, t - 128);
            else if (t < 384) v = load_f(b3, isbf, t - 256);
            else if (t < 640) v = load_f(Wo, isbf, t - 384);
            else v = load_f(bo, isbf, t - 640);
            smalls[t] = v;
        } else if (t >= 642 && t < 706) {
            xb[(size_t)N * 64 + (t - 642)] = 0;  // zero row N (masked-gather target)
        }
        return;
    }

    // ---- scatter role ----
    int is64, isbf;
    self_detect(ei, nullptr, is64, isbf);
    int cbase = (blk - (cvb + 13)) * CH;
    int cn = E - cbase;
    if (cn > CH) cn = CH;
    lhist[t] = 0;
    __syncthreads();
    int mysrc[4], myb[4], mydl[4];
#pragma unroll
    for (int k = 0; k < 4; ++k) {
        int i = t + k * 1024;
        myb[k] = -1;
        if (i < cn) {
            int e = cbase + i;
            int s = load_id(ei, is64, (size_t)e, N);
            int d = load_id(ei, is64, (size_t)E + e, N);
            mysrc[k] = s;
            mydl[k] = d & 255;
            myb[k] = d >> 8;
            atomicAdd(&lhist[myb[k]], 1);
        }
    }
    __syncthreads();
    int lane = t & 63, wid = t >> 6;
    int v = lhist[t];
    int inc = v;
#pragma unroll
    for (int off = 1; off < 64; off <<= 1) {
        int o = __shfl_up(inc, off);
        if (lane >= off) inc += o;
    }
    if (lane == 63) wsum[wid] = inc;
    __syncthreads();
    int wpre = 0;
    for (int w = 0; w < wid; ++w) wpre += wsum[w];
    int excl = wpre + inc - v;
    loff[t] = excl;
    lcur[t] = excl;
    if (v > 0) gofs[t] = atomicAdd(&gcur[t], v);
    __syncthreads();
#pragma unroll
    for (int k = 0; k < 4; ++k) {
        if (myb[k] >= 0) {
            int pos = atomicAdd(&lcur[myb[k]], 1);
            ebuf[pos] = (u32)mysrc[k] | ((u32)mydl[k] << 24);
            ebkt[pos] = (u16)myb[k];
        }
    }
    __syncthreads();
#pragma unroll
    for (int k = 0; k < 4; ++k) {
        int i = t + k * 1024;
        if (i < cn) {
            int bb = ebkt[i];
            int local = gofs[bb] + (i - loff[bb]);
            if (local < CAPB) csrbkt[(size_t)bb * CAPB + local] = ebuf[i];
        }
    }
}

// one block per bucket: counting-sort by dst-low, compact into csr via gtot cursor
__global__ void csr_build_kernel(const u32* __restrict__ csrbkt, const int* __restrict__ gcur,
                                 int N, int* __restrict__ gtot,
                                 int* __restrict__ offs, int* __restrict__ cnt,
                                 int* __restrict__ csr) {
    __shared__ int lh[256], lcur[256], wsum[4];
    __shared__ int sbase;
    __shared__ u32 sbuf[CAPB];
    int t = threadIdx.x;  // 256
    int b = blockIdx.x;
    int cb = gcur[b];
    if (cb > CAPB) cb = CAPB;
    const u32* bsrc = csrbkt + (size_t)b * CAPB;
    int d0 = b << 8;
    lh[t] = 0;
    __syncthreads();
    for (int i = t; i < cb; i += 256) atomicAdd(&lh[bsrc[i] >> 24], 1);
    __syncthreads();
    int lane = t & 63, wid = t >> 6;
    int v = lh[t];
    int inc = v;
#pragma unroll
    for (int off = 1; off < 64; off <<= 1) {
        int o = __shfl_up(inc, off);
        if (lane >= off) inc += o;
    }
    if (lane == 63) wsum[wid] = inc;
    __syncthreads();
    int wpre = 0;
    for (int w = 0; w < wid; ++w) wpre += wsum[w];
    int excl = wpre + inc - v;
    lcur[t] = excl;
    if (t == 0) sbase = atomicAdd(gtot, cb);
    __syncthreads();
    int base = sbase;
    int d = d0 + t;
    if (d < N) {
        offs[d] = base + excl;
        cnt[d] = v;
    }
    for (int i = t; i < cb; i += 256) {
        u32 e = bsrc[i];
        int pos = atomicAdd(&lcur[e >> 24], 1);
        sbuf[pos] = e & 0xFFFFFFu;
    }
    __syncthreads();
    for (int i = t; i < cb; i += 256) csr[base + i] = (int)sbuf[i];
}

// ---------------- aggregation v3: burst batch-0 + exact tails ----------------
// Same grid/mapping as proven round-0 (8*tstride blocks, 4 waves x 4 nodes).
// Per wave: batch-0 = first 8 edges of ALL 4 nodes issued as one 16-deep
// dwordx2 burst (32 lanes/row, halves take even/odd edges; 128 B/lane in
// flight, one exposed latency for ~86% of edges). Accumulation per node in
// issue order -> compiler emits counted vmcnt. Tails (deg > 8) are exact
// per-node loops, wave-uniform trip counts. Masked slots gather row N
// (zeroed by front) -> no data masking; u32 byte offsets (N*256 < 2^31).
// csr over-allocated by CAPB+64 -> padded csr reads never OOB; padded
// VALUES unused (masked to zero row).

__global__ void agg_kernel(const u32* __restrict__ F2, const int* __restrict__ offs,
                           const int* __restrict__ cnt, const int* __restrict__ csr,
                           u32* __restrict__ Aout, int N, int tstride) {
    int sub = blockIdx.x / tstride;
    int tile = blockIdx.x % tstride;
    int w = threadIdx.x >> 6;
    int lane = threadIdx.x & 63;
    int li = lane & 31;
    int half = lane >> 5;
    int nd0 = tile * 128 + sub * 16 + w * 4;
    if (nd0 >= N) return;

    int st[4], ct[4];
#pragma unroll
    for (int j = 0; j < 4; ++j) {
        int nd = nd0 + j;
        st[j] = (nd < N) ? offs[nd] : 0;
        ct[j] = (nd < N) ? cnt[nd] : 0;
    }

    float acc[4][4];
#pragma unroll
    for (int j = 0; j < 4; ++j)
#pragma unroll
        for (int f = 0; f < 4; ++f) acc[j][f] = 0.f;

    const char* fb = (const char*)F2;
    u32 li8 = (u32)li * 8u;
    u32 zoff = ((u32)N << 8) + li8;  // zero-row byte offset

    // ---- batch 0: 16 dwordx2 gathers in flight ----
    u32 ax[4][4], ay[4][4];
#pragma unroll
    for (int j = 0; j < 4; ++j) {
        int cb = st[j] + half;
#pragma unroll
        for (int k = 0; k < 4; ++k) {
            u32 sv = (u32)csr[cb + 2 * k];  // padded reads safe (over-alloc)
            int e = 2 * k + half;
            u32 off = (e < ct[j]) ? ((sv << 8) + li8) : zoff;
            uint2 u = *reinterpret_cast<const uint2*>(fb + off);
            ax[j][k] = u.x;
            ay[j][k] = u.y;
        }
    }
#pragma unroll
    for (int j = 0; j < 4; ++j) {
#pragma unroll
        for (int k = 0; k < 4; ++k) {
            acc[j][0] += lo2f(ax[j][k]);
            acc[j][1] += hi2f(ax[j][k]);
            acc[j][2] += lo2f(ay[j][k]);
            acc[j][3] += hi2f(ay[j][k]);
        }
    }

    // ---- exact tails (deg > 8), wave-uniform trip counts ----
#pragma unroll 1
    for (int j = 0; j < 4; ++j) {
#pragma unroll 1
        for (int pos = 8; pos < ct[j]; pos += 8) {
            int cb = st[j] + pos + half;
            int rem = ct[j] - pos;
            u32 tx[4], ty[4];
#pragma unroll
            for (int k = 0; k < 4; ++k) {
                u32 sv = (u32)csr[cb + 2 * k];
                u32 off = ((2 * k + half) < rem) ? ((sv << 8) + li8) : zoff;
                uint2 u = *reinterpret_cast<const uint2*>(fb + off);
                tx[k] = u.x;
                ty[k] = u.y;
            }
#pragma unroll
            for (int k = 0; k < 4; ++k) {
                acc[j][0] += lo2f(tx[k]);
                acc[j][1] += hi2f(tx[k]);
                acc[j][2] += lo2f(ty[k]);
                acc[j][3] += hi2f(ty[k]);
            }
        }
    }

    // combine the two wave halves (disjoint edge subsets)
#pragma unroll
    for (int j = 0; j < 4; ++j)
#pragma unroll
        for (int f = 0; f < 4; ++f) acc[j][f] += __shfl_xor(acc[j][f], 32);

    if (half == 0) {
#pragma unroll
        for (int j = 0; j < 4; ++j) {
            int nd = nd0 + j;
            if (nd < N) {
                float sc = 1.0f / (float)(ct[j] > 1 ? ct[j] : 1);
                u32 o0 = (u32)f2b(acc[j][0] * sc) | ((u32)f2b(acc[j][1] * sc) << 16);
                u32 o1 = (u32)f2b(acc[j][2] * sc) | ((u32)f2b(acc[j][3] * sc) << 16);
                *reinterpret_cast<uint2*>(Aout + ((size_t)nd * 64 + li * 2)) =
                    make_uint2(o0, o1);
            }
        }
    }
}

// ---------------- dual-GEMM (proven): F = act(concat(agg,F) @ Wc + b), IN-PLACE ----------------
__global__ void gemm_kernel(const u32* __restrict__ aggb, u32* Fio,
                            const u16* __restrict__ Wcp, const float* __restrict__ biasf,
                            int N, int relu, const float* __restrict__ headw,
                            const u32* __restrict__ xw, void* __restrict__ outp) {
    int tid = threadIdx.x;
    int w = tid >> 6;
    int lane = tid & 63;
    int nbase = blockIdx.x * 128;
    int n = lane & 31;
    int q = lane >> 5;
    int rowl = w * 32 + n;
    int node = nbase + rowl;
    int nodeC = (node < N) ? node : (N - 1);
    const u32* aRow = aggb + (size_t)nodeC * 64 + q * 4;
    const u32* fRow = Fio + (size_t)nodeC * 64 + q * 4;

    floatx16 acc0 = 0.0f, acc1 = 0.0f, acc2 = 0.0f, acc3 = 0.0f;

#pragma unroll
    for (int s = 0; s < 16; ++s) {
        const u32* ap = (s < 8) ? (aRow + (size_t)s * 8) : (fRow + (size_t)(s - 8) * 8);
        bf16x8 a = *reinterpret_cast<const bf16x8*>(ap);
        const u16* bp = Wcp + (size_t)((s * 4) * 64 + lane) * 8;
        bf16x8 b0 = *reinterpret_cast<const bf16x8*>(bp);
        bf16x8 b1 = *reinterpret_cast<const bf16x8*>(bp + 64 * 8);
        bf16x8 b2 = *reinterpret_cast<const bf16x8*>(bp + 2 * 64 * 8);
        bf16x8 b3 = *reinterpret_cast<const bf16x8*>(bp + 3 * 64 * 8);
        acc0 = __builtin_amdgcn_mfma_f32_32x32x16_bf16(a, b0, acc0, 0, 0, 0);
        acc1 = __builtin_amdgcn_mfma_f32_32x32x16_bf16(a, b1, acc1, 0, 0, 0);
        acc2 = __builtin_amdgcn_mfma_f32_32x32x16_bf16(a, b2, acc2, 0, 0, 0);
        acc3 = __builtin_amdgcn_mfma_f32_32x32x16_bf16(a, b3, acc3, 0, 0, 0);
    }

    int mbase = nbase + w * 32;
    floatx16 accs[4] = {acc0, acc1, acc2, acc3};
    // C/D: col=lane&31, row=(r&3)+8*(r>>2)+4*(lane>>5)  [verified m74/m101]

    if (outp == nullptr) {
#pragma unroll
        for (int jt = 0; jt < 4; ++jt) {
            int j0 = jt * 32 + n;
            float bf = biasf[j0];
#pragma unroll
            for (int r = 0; r < 16; ++r) {
                int row = (r & 3) + 8 * (r >> 2) + 4 * q;
                int nodeS = mbase + row;
                if (nodeS < N) {
                    float v = accs[jt][r] + bf;
                    if (relu) v = fmaxf(v, 0.0f);
                    u16* dst16 = (u16*)&Fio[(size_t)nodeS * 64];
                    dst16[j0] = f2b(v);
                }
            }
        }
    } else {
        // fused head: out[node] = (h·Wo0 + bo0, h·Wo1 + bo1); h = acc + bl3
        int is64, isbf;
        self_detect(nullptr, xw, is64, isbf);  // full wave active here
#pragma unroll
        for (int r = 0; r < 16; ++r) {
            float p0 = 0.f, p1 = 0.f;
#pragma unroll
            for (int jt = 0; jt < 4; ++jt) {
                int j = jt * 32 + n;
                float v = accs[jt][r] + biasf[j];
                p0 += v * headw[j];
                p1 += v * headw[128 + j];
            }
#pragma unroll
            for (int off = 16; off > 0; off >>= 1) {
                p0 += __shfl_xor(p0, off);
                p1 += __shfl_xor(p1, off);
            }
            if (n == 0) {
                int row = (r & 3) + 8 * (r >> 2) + 4 * q;
                int nodeS = mbase + row;
                if (nodeS < N) {
                    float o0 = p0 + headw[256];  // bo0
                    float o1 = p1 + headw[257];  // bo1
                    if (isbf)
                        ((u32*)outp)[nodeS] = (u32)f2b(o0) | ((u32)f2b(o1) << 16);
                    else
                        ((float2*)outp)[nodeS] = make_float2(o0, o1);
                }
            }
        }
    }
}

extern "C" void kernel_launch(void* const* d_in, const int* in_sizes, int n_in,
                              void* d_out, int out_size, void* d_ws, size_t ws_size,
                              hipStream_t stream) {
    const int N = in_sizes[0] / 128;
    const int E = in_sizes[1] / 2;

    const void* x = d_in[0];
    const int* ei = (const int*)d_in[1];
    const void* Wl[3] = {d_in[2], d_in[5], d_in[8]};
    const void* bl[3] = {d_in[3], d_in[6], d_in[9]};
    const void* Wr[3] = {d_in[4], d_in[7], d_in[10]};
    const void* Wo = d_in[11];
    const void* bo = d_in[12];

    // workspace bump allocator (256B aligned)
    char* p = (char*)d_ws;
    auto alloc = [&](size_t bytes) -> char* {
        char* r = p;
        p += (bytes + 255) & ~(size_t)255;
        return r;
    };
    int* offs = (int*)alloc((size_t)N * 4);
    int* cnt = (int*)alloc((size_t)N * 4);
    float* smalls = (float*)alloc(642 * 4);
    int* gcur = (int*)alloc(1025 * 4);  // [1024] = gtot
    int* csr = (int*)alloc(((size_t)E + CAPB + 64) * 4);  // over-alloc: padded reads safe
    u16* Wcp = (u16*)alloc((size_t)3 * 4096 * 8 * 2);
    u32* xb = (u32*)alloc((size_t)(N + 1) * 64 * 4);  // +1: zero row for masked gathers
    u32* aggb = (u32*)alloc((size_t)N * 64 * 4);      // agg features; aliased as csrbkt during build
    u32* csrbkt = aggb;                                // dead until layers start
    int* gtot = gcur + 1024;
    (void)ws_size;

    const int NB = (N + 255) / 256;          // buckets
    const int cvb = (N * 16 + 1023) / 1024;  // convert blocks (1024 thr)
    const int sb = (E + CH - 1) / CH;        // scatter blocks
    const int gb = (N + 127) / 128;          // gemm blocks (tiles)
    const int tstride = (gb + 7) & ~7;       // tile stride, mult of 8 (XCD affinity)
    const int ab = 8 * tstride;              // agg blocks: 8 sub-blocks x tstride tiles

    hipMemsetAsync(gcur, 0, 1025 * 4, stream);
    front_kernel<<<cvb + 13 + sb, 1024, 0, stream>>>(
        x, ei, E, N, cvb, xb, gcur, csrbkt,
        Wl[0], Wr[0], Wl[1], Wr[1], Wl[2], Wr[2],
        bl[0], bl[1], bl[2], Wo, bo, Wcp, smalls);
    csr_build_kernel<<<NB, 256, 0, stream>>>(csrbkt, gcur, N, gtot, offs, cnt, csr);

    // layer 1
    agg_kernel<<<ab, 256, 0, stream>>>(xb, offs, cnt, csr, aggb, N, tstride);
    gemm_kernel<<<gb, 256, 0, stream>>>(aggb, xb, Wcp, smalls, N, 1, nullptr, nullptr, nullptr);
    // layer 2
    agg_kernel<<<ab, 256, 0, stream>>>(xb, offs, cnt, csr, aggb, N, tstride);
    gemm_kernel<<<gb, 256, 0, stream>>>(aggb, xb, Wcp + 32768, smalls + 128, N, 1, nullptr, nullptr, nullptr);
    // layer 3 + fused head
    agg_kernel<<<ab, 256, 0, stream>>>(xb, offs, cnt, csr, aggb, N, tstride);
    gemm_kernel<<<gb, 256, 0, stream>>>(aggb, xb, Wcp + 65536, smalls + 256, N, 0,
                                        smalls + 384, (const u32*)x, d_out);
}

// Round 4
// 339.146 us; speedup vs baseline: 1.1514x; 1.0230x over previous
//
#include <hip/hip_runtime.h>
#include <stdint.h>

typedef unsigned int u32;
typedef unsigned short u16;
typedef __bf16 bf16x8 __attribute__((ext_vector_type(8)));
typedef float floatx16 __attribute__((ext_vector_type(16)));
typedef u32 u32x4 __attribute__((ext_vector_type(4)));
typedef float floatx4 __attribute__((ext_vector_type(4)));

__device__ __forceinline__ u16 f2b(float f) {
    u32 u = __builtin_bit_cast(u32, f);
    u32 r = u + 0x7FFFu + ((u >> 16) & 1u);
    return (u16)(r >> 16);
}
__device__ __forceinline__ float lo2f(u32 u) { return __builtin_bit_cast(float, u << 16); }
__device__ __forceinline__ float hi2f(u32 u) { return __builtin_bit_cast(float, u & 0xFFFF0000u); }

// ---------------- wave-uniform self-detection ----------------
__device__ __forceinline__ void self_detect(const int* ei, const u32* xw, int& is64, int& isbf) {
    int lane = threadIdx.x & 63;
    int v = ei ? ei[2 * lane + 1] : 0;
    unsigned long long b1 = __ballot(v == 0);
    u32 w = xw ? xw[lane] : 0;
    u32 e = (w >> 7) & 0xFF;
    int plaus = (e == 0) || (e >= 90 && e <= 140);
    unsigned long long b2 = __ballot(plaus);
    is64 = (b1 == ~0ULL) ? 1 : 0;
    isbf = (b2 == ~0ULL) ? 1 : 0;
}

__device__ __forceinline__ int load_id(const int* __restrict__ ei, int is64, size_t pos, int N) {
    int v = is64 ? ei[2 * pos] : ei[pos];
    unsigned u = (unsigned)v;
    if (u >= (unsigned)N) u = 0;  // clamp: never OOB
    return (int)u;
}

__device__ __forceinline__ float load_f(const void* __restrict__ p, int isbf, size_t i) {
    if (isbf) {
        u16 s = ((const u16*)p)[i];
        return __builtin_bit_cast(float, ((u32)s) << 16);
    }
    return ((const float*)p)[i];
}

// ---------------- merged front: convert_x + wprep + smalls + bucket_scatter ----------------
// (proven round-0 structure; scatter edge loads vectorized to uint2 for is64)
#define CH 4096
#define CAPB 3072

__global__ __launch_bounds__(1024) void front_kernel(
    const void* __restrict__ xraw, const int* __restrict__ ei, int E, int N, int cvb,
    u32* __restrict__ xb, int* __restrict__ gcur, u32* __restrict__ csrbkt,
    const void* Wl1, const void* Wr1, const void* Wl2, const void* Wr2,
    const void* Wl3, const void* Wr3, const void* b1, const void* b2,
    const void* b3, const void* Wo, const void* bo,
    u16* __restrict__ Wcp, float* __restrict__ smalls) {
    __shared__ int lhist[1024], loff[1024], lcur[1024], gofs[1024], wsum[16];
    __shared__ u32 ebuf[CH];
    __shared__ u16 ebkt[CH];
    int blk = blockIdx.x;
    int t = threadIdx.x;

    if (blk < cvb) {
        int is64, isbf;
        self_detect(nullptr, (const u32*)xraw, is64, isbf);
        int i = blk * 1024 + t;
        int count4 = N * 16;
        if (i >= count4) return;
        if (isbf) {
            ((u32x4*)xb)[i] = ((const u32x4*)xraw)[i];
        } else {
            const floatx4* f4 = (const floatx4*)xraw;
            floatx4 f0 = f4[2 * i], f1 = f4[2 * i + 1];
            u32x4 o;
            o.x = (u32)f2b(f0.x) | ((u32)f2b(f0.y) << 16);
            o.y = (u32)f2b(f0.z) | ((u32)f2b(f0.w) << 16);
            o.z = (u32)f2b(f1.x) | ((u32)f2b(f1.y) << 16);
            o.w = (u32)f2b(f1.z) | ((u32)f2b(f1.w) << 16);
            ((u32x4*)xb)[i] = o;
        }
        return;
    }
    if (blk < cvb + 12) {
        int is64, isbf;
        self_detect(nullptr, (const u32*)xraw, is64, isbf);
        int tg = (blk - cvb) * 1024 + t;  // 0..12287
        int l = tg >> 12;
        int tt = tg & 4095;
        const void* Wl = (l == 0) ? Wl1 : (l == 1) ? Wl2 : Wl3;
        const void* Wr = (l == 0) ? Wr1 : (l == 1) ? Wr2 : Wr3;
        u16* Wout = Wcp + (size_t)l * 32768;
        int lane = tt & 63;
        int jt = (tt >> 6) & 3;
        int s = tt >> 8;
        int n = lane & 31;
        int q = lane >> 5;
        int j = jt * 32 + n;
#pragma unroll
        for (int jj = 0; jj < 8; ++jj) {
            int k = s * 16 + q * 8 + jj;
            float v = (k < 128) ? load_f(Wl, isbf, (size_t)j * 128 + k)
                                : load_f(Wr, isbf, (size_t)j * 128 + (k - 128));
            Wout[tt * 8 + jj] = f2b(v);
        }
        return;
    }
    if (blk == cvb + 12) {
        int is64, isbf;
        self_detect(nullptr, (const u32*)xraw, is64, isbf);
        if (t < 642) {
            float v;
            if (t < 128) v = load_f(b1, isbf, t);
            else if (t < 256) v = load_f(b2, isbf, t - 128);
            else if (t < 384) v = load_f(b3, isbf, t - 256);
            else if (t < 640) v = load_f(Wo, isbf, t - 384);
            else v = load_f(bo, isbf, t - 640);
            smalls[t] = v;
        }
        return;
    }

    // ---- scatter role ----
    int is64, isbf;
    self_detect(ei, nullptr, is64, isbf);
    int cbase = (blk - (cvb + 13)) * CH;
    int cn = E - cbase;
    if (cn > CH) cn = CH;
    lhist[t] = 0;
    __syncthreads();
    int mysrc[4], myb[4], mydl[4];
#pragma unroll
    for (int k = 0; k < 4; ++k) {
        int i = t + k * 1024;
        myb[k] = -1;
        if (i < cn) {
            int e = cbase + i;
            int s, d;
            if (is64) {
                s = (int)((const uint2*)ei)[(size_t)e].x;
                d = (int)((const uint2*)ei)[(size_t)E + e].x;
            } else {
                s = ei[(size_t)e];
                d = ei[(size_t)E + e];
            }
            if ((unsigned)s >= (unsigned)N) s = 0;
            if ((unsigned)d >= (unsigned)N) d = 0;
            mysrc[k] = s;
            mydl[k] = d & 255;
            myb[k] = d >> 8;
            atomicAdd(&lhist[myb[k]], 1);
        }
    }
    __syncthreads();
    int lane = t & 63, wid = t >> 6;
    int v = lhist[t];
    int inc = v;
#pragma unroll
    for (int off = 1; off < 64; off <<= 1) {
        int o = __shfl_up(inc, off);
        if (lane >= off) inc += o;
    }
    if (lane == 63) wsum[wid] = inc;
    __syncthreads();
    int wpre = 0;
    for (int w = 0; w < wid; ++w) wpre += wsum[w];
    int excl = wpre + inc - v;
    loff[t] = excl;
    lcur[t] = excl;
    if (v > 0) gofs[t] = atomicAdd(&gcur[t], v);
    __syncthreads();
#pragma unroll
    for (int k = 0; k < 4; ++k) {
        if (myb[k] >= 0) {
            int pos = atomicAdd(&lcur[myb[k]], 1);
            ebuf[pos] = (u32)mysrc[k] | ((u32)mydl[k] << 24);
            ebkt[pos] = (u16)myb[k];
        }
    }
    __syncthreads();
    // write runs: consecutive i within a bucket -> consecutive global slots
#pragma unroll
    for (int k = 0; k < 4; ++k) {
        int i = t + k * 1024;
        if (i < cn) {
            int bb = ebkt[i];
            int local = gofs[bb] + (i - loff[bb]);
            if (local < CAPB) csrbkt[(size_t)bb * CAPB + local] = ebuf[i];
        }
    }
}

// one block per bucket: counting-sort by dst-low, compact into csr via gtot cursor
__global__ void csr_build_kernel(const u32* __restrict__ csrbkt, const int* __restrict__ gcur,
                                 int N, int* __restrict__ gtot,
                                 int* __restrict__ offs, int* __restrict__ cnt,
                                 int* __restrict__ csr) {
    __shared__ int lh[256], lcur[256], wsum[4];
    __shared__ int sbase;
    __shared__ u32 sbuf[CAPB];
    int t = threadIdx.x;  // 256
    int b = blockIdx.x;
    int cb = gcur[b];
    if (cb > CAPB) cb = CAPB;
    const u32* bsrc = csrbkt + (size_t)b * CAPB;
    int d0 = b << 8;
    lh[t] = 0;
    __syncthreads();
    for (int i = t; i < cb; i += 256) atomicAdd(&lh[bsrc[i] >> 24], 1);
    __syncthreads();
    int lane = t & 63, wid = t >> 6;
    int v = lh[t];
    int inc = v;
#pragma unroll
    for (int off = 1; off < 64; off <<= 1) {
        int o = __shfl_up(inc, off);
        if (lane >= off) inc += o;
    }
    if (lane == 63) wsum[wid] = inc;
    __syncthreads();
    int wpre = 0;
    for (int w = 0; w < wid; ++w) wpre += wsum[w];
    int excl = wpre + inc - v;
    lcur[t] = excl;
    if (t == 0) sbase = atomicAdd(gtot, cb);
    __syncthreads();
    int base = sbase;
    int d = d0 + t;
    if (d < N) {
        offs[d] = base + excl;
        cnt[d] = v;
    }
    for (int i = t; i < cb; i += 256) {
        u32 e = bsrc[i];
        int pos = atomicAdd(&lcur[e >> 24], 1);
        sbuf[pos] = e & 0xFFFFFFu;
    }
    __syncthreads();
    for (int i = t; i < cb; i += 256) csr[base + i] = (int)sbuf[i];
}

// ---------------- aggregation (round-0 proven form, best measured 42.9 µs) ----------------
// XCD-affine tiling, 4 nodes/wave processed serially, 8-deep unrolled gather.
// grid = 8 * tstride; block b: sub = b / tstride, tile = b % tstride; handles
// nodes [tile*128 + sub*16, +16). All 8 sub-blocks of gemm tile T land on the
// same XCD as gemm block T (blockIdx%8 heuristic) -> aggb produced L2-hot.

__global__ void agg_kernel(const u32* __restrict__ F2, const int* __restrict__ offs,
                           const int* __restrict__ cnt, const int* __restrict__ csr,
                           u32* __restrict__ Aout, int N, int tstride) {
    int sub = blockIdx.x / tstride;
    int tile = blockIdx.x % tstride;
    int w = threadIdx.x >> 6;
    int lane = threadIdx.x & 63;
    int nd0 = tile * 128 + sub * 16 + w * 4;
    if (nd0 >= N) return;
    int nd1 = nd0 + 4 < N ? nd0 + 4 : N;
    for (int nd = nd0; nd < nd1; ++nd) {
        int start = offs[nd];
        int num = cnt[nd];
        float a0 = 0.f, a1 = 0.f;
        int i = 0;
        for (; i + 8 <= num; i += 8) {
            int s0 = csr[start + i + 0], s1 = csr[start + i + 1];
            int s2 = csr[start + i + 2], s3 = csr[start + i + 3];
            int s4 = csr[start + i + 4], s5 = csr[start + i + 5];
            int s6 = csr[start + i + 6], s7 = csr[start + i + 7];
            u32 u0 = F2[(size_t)s0 * 64 + lane];
            u32 u1 = F2[(size_t)s1 * 64 + lane];
            u32 u2 = F2[(size_t)s2 * 64 + lane];
            u32 u3 = F2[(size_t)s3 * 64 + lane];
            u32 u4 = F2[(size_t)s4 * 64 + lane];
            u32 u5 = F2[(size_t)s5 * 64 + lane];
            u32 u6 = F2[(size_t)s6 * 64 + lane];
            u32 u7 = F2[(size_t)s7 * 64 + lane];
            a0 += lo2f(u0) + lo2f(u1) + lo2f(u2) + lo2f(u3) +
                  lo2f(u4) + lo2f(u5) + lo2f(u6) + lo2f(u7);
            a1 += hi2f(u0) + hi2f(u1) + hi2f(u2) + hi2f(u3) +
                  hi2f(u4) + hi2f(u5) + hi2f(u6) + hi2f(u7);
        }
        for (; i + 4 <= num; i += 4) {
            int s0 = csr[start + i + 0], s1 = csr[start + i + 1];
            int s2 = csr[start + i + 2], s3 = csr[start + i + 3];
            u32 u0 = F2[(size_t)s0 * 64 + lane];
            u32 u1 = F2[(size_t)s1 * 64 + lane];
            u32 u2 = F2[(size_t)s2 * 64 + lane];
            u32 u3 = F2[(size_t)s3 * 64 + lane];
            a0 += lo2f(u0) + lo2f(u1) + lo2f(u2) + lo2f(u3);
            a1 += hi2f(u0) + hi2f(u1) + hi2f(u2) + hi2f(u3);
        }
        for (; i < num; ++i) {
            u32 u = F2[(size_t)csr[start + i] * 64 + lane];
            a0 += lo2f(u);
            a1 += hi2f(u);
        }
        float sc = 1.0f / (float)(num > 1 ? num : 1);
        a0 *= sc;
        a1 *= sc;
        Aout[(size_t)nd * 64 + lane] = (u32)f2b(a0) | ((u32)f2b(a1) << 16);
    }
}

// ---------------- dual-GEMM (proven): F = act(concat(agg,F) @ Wc + b), IN-PLACE ----------------
__global__ void gemm_kernel(const u32* __restrict__ aggb, u32* Fio,
                            const u16* __restrict__ Wcp, const float* __restrict__ biasf,
                            int N, int relu, const float* __restrict__ headw,
                            const u32* __restrict__ xw, void* __restrict__ outp) {
    int tid = threadIdx.x;
    int w = tid >> 6;
    int lane = tid & 63;
    int nbase = blockIdx.x * 128;
    int n = lane & 31;
    int q = lane >> 5;
    int rowl = w * 32 + n;
    int node = nbase + rowl;
    int nodeC = (node < N) ? node : (N - 1);
    const u32* aRow = aggb + (size_t)nodeC * 64 + q * 4;
    const u32* fRow = Fio + (size_t)nodeC * 64 + q * 4;

    floatx16 acc0 = 0.0f, acc1 = 0.0f, acc2 = 0.0f, acc3 = 0.0f;

#pragma unroll
    for (int s = 0; s < 16; ++s) {
        const u32* ap = (s < 8) ? (aRow + (size_t)s * 8) : (fRow + (size_t)(s - 8) * 8);
        bf16x8 a = *reinterpret_cast<const bf16x8*>(ap);
        const u16* bp = Wcp + (size_t)((s * 4) * 64 + lane) * 8;
        bf16x8 b0 = *reinterpret_cast<const bf16x8*>(bp);
        bf16x8 b1 = *reinterpret_cast<const bf16x8*>(bp + 64 * 8);
        bf16x8 b2 = *reinterpret_cast<const bf16x8*>(bp + 2 * 64 * 8);
        bf16x8 b3 = *reinterpret_cast<const bf16x8*>(bp + 3 * 64 * 8);
        acc0 = __builtin_amdgcn_mfma_f32_32x32x16_bf16(a, b0, acc0, 0, 0, 0);
        acc1 = __builtin_amdgcn_mfma_f32_32x32x16_bf16(a, b1, acc1, 0, 0, 0);
        acc2 = __builtin_amdgcn_mfma_f32_32x32x16_bf16(a, b2, acc2, 0, 0, 0);
        acc3 = __builtin_amdgcn_mfma_f32_32x32x16_bf16(a, b3, acc3, 0, 0, 0);
    }

    int mbase = nbase + w * 32;
    floatx16 accs[4] = {acc0, acc1, acc2, acc3};
    // C/D: col=lane&31, row=(r&3)+8*(r>>2)+4*(lane>>5)  [verified m74/m101]

    if (outp == nullptr) {
#pragma unroll
        for (int jt = 0; jt < 4; ++jt) {
            int j0 = jt * 32 + n;
            float bf = biasf[j0];
#pragma unroll
            for (int r = 0; r < 16; ++r) {
                int row = (r & 3) + 8 * (r >> 2) + 4 * q;
                int nodeS = mbase + row;
                if (nodeS < N) {
                    float v = accs[jt][r] + bf;
                    if (relu) v = fmaxf(v, 0.0f);
                    u16* dst16 = (u16*)&Fio[(size_t)nodeS * 64];
                    dst16[j0] = f2b(v);
                }
            }
        }
    } else {
        // fused head: out[node] = (h·Wo0 + bo0, h·Wo1 + bo1); h = acc + bl3
        int is64, isbf;
        self_detect(nullptr, xw, is64, isbf);  // full wave active here
#pragma unroll
        for (int r = 0; r < 16; ++r) {
            float p0 = 0.f, p1 = 0.f;
#pragma unroll
            for (int jt = 0; jt < 4; ++jt) {
                int j = jt * 32 + n;
                float v = accs[jt][r] + biasf[j];
                p0 += v * headw[j];
                p1 += v * headw[128 + j];
            }
#pragma unroll
            for (int off = 16; off > 0; off >>= 1) {
                p0 += __shfl_xor(p0, off);
                p1 += __shfl_xor(p1, off);
            }
            if (n == 0) {
                int row = (r & 3) + 8 * (r >> 2) + 4 * q;
                int nodeS = mbase + row;
                if (nodeS < N) {
                    float o0 = p0 + headw[256];  // bo0
                    float o1 = p1 + headw[257];  // bo1
                    if (isbf)
                        ((u32*)outp)[nodeS] = (u32)f2b(o0) | ((u32)f2b(o1) << 16);
                    else
                        ((float2*)outp)[nodeS] = make_float2(o0, o1);
                }
            }
        }
    }
}

extern "C" void kernel_launch(void* const* d_in, const int* in_sizes, int n_in,
                              void* d_out, int out_size, void* d_ws, size_t ws_size,
                              hipStream_t stream) {
    const int N = in_sizes[0] / 128;
    const int E = in_sizes[1] / 2;

    const void* x = d_in[0];
    const int* ei = (const int*)d_in[1];
    const void* Wl[3] = {d_in[2], d_in[5], d_in[8]};
    const void* bl[3] = {d_in[3], d_in[6], d_in[9]};
    const void* Wr[3] = {d_in[4], d_in[7], d_in[10]};
    const void* Wo = d_in[11];
    const void* bo = d_in[12];

    // workspace bump allocator (256B aligned)
    char* p = (char*)d_ws;
    auto alloc = [&](size_t bytes) -> char* {
        char* r = p;
        p += (bytes + 255) & ~(size_t)255;
        return r;
    };
    int* offs = (int*)alloc((size_t)N * 4);
    int* cnt = (int*)alloc((size_t)N * 4);
    float* smalls = (float*)alloc(642 * 4);
    int* gcur = (int*)alloc(1025 * 4);  // [1024] = gtot
    int* csr = (int*)alloc(((size_t)E + CAPB + 64) * 4);  // over-alloc: padded reads safe
    u16* Wcp = (u16*)alloc((size_t)3 * 4096 * 8 * 2);
    u32* xb = (u32*)alloc((size_t)(N + 1) * 64 * 4);
    u32* aggb = (u32*)alloc((size_t)N * 64 * 4);  // agg features; aliased as csrbkt during build
    u32* csrbkt = aggb;                            // dead until layers start
    int* gtot = gcur + 1024;
    (void)ws_size;

    const int NB = (N + 255) / 256;          // buckets
    const int cvb = (N * 16 + 1023) / 1024;  // convert blocks (1024 thr)
    const int sb = (E + CH - 1) / CH;        // scatter blocks
    const int gb = (N + 127) / 128;          // gemm blocks (tiles)
    const int tstride = (gb + 7) & ~7;       // tile stride, mult of 8 (XCD affinity)
    const int ab = 8 * tstride;              // agg blocks: 8 sub-blocks x tstride tiles

    hipMemsetAsync(gcur, 0, 1025 * 4, stream);
    front_kernel<<<cvb + 13 + sb, 1024, 0, stream>>>(
        x, ei, E, N, cvb, xb, gcur, csrbkt,
        Wl[0], Wr[0], Wl[1], Wr[1], Wl[2], Wr[2],
        bl[0], bl[1], bl[2], Wo, bo, Wcp, smalls);
    csr_build_kernel<<<NB, 256, 0, stream>>>(csrbkt, gcur, N, gtot, offs, cnt, csr);

    // layer 1
    agg_kernel<<<ab, 256, 0, stream>>>(xb, offs, cnt, csr, aggb, N, tstride);
    gemm_kernel<<<gb, 256, 0, stream>>>(aggb, xb, Wcp, smalls, N, 1, nullptr, nullptr, nullptr);
    // layer 2
    agg_kernel<<<ab, 256, 0, stream>>>(xb, offs, cnt, csr, aggb, N, tstride);
    gemm_kernel<<<gb, 256, 0, stream>>>(aggb, xb, Wcp + 32768, smalls + 128, N, 1, nullptr, nullptr, nullptr);
    // layer 3 + fused head
    agg_kernel<<<ab, 256, 0, stream>>>(xb, offs, cnt, csr, aggb, N, tstride);
    gemm_kernel<<<gb, 256, 0, stream>>>(aggb, xb, Wcp + 65536, smalls + 256, N, 0,
                                        smalls + 384, (const u32*)x, d_out);
}

// Round 5
// 339.110 us; speedup vs baseline: 1.1516x; 1.0001x over previous
//
#include <hip/hip_runtime.h>
#include <stdint.h>

typedef unsigned int u32;
typedef unsigned short u16;
typedef __bf16 bf16x8 __attribute__((ext_vector_type(8)));
typedef float floatx16 __attribute__((ext_vector_type(16)));
typedef u32 u32x4 __attribute__((ext_vector_type(4)));
typedef float floatx4 __attribute__((ext_vector_type(4)));

__device__ __forceinline__ u16 f2b(float f) {
    u32 u = __builtin_bit_cast(u32, f);
    u32 r = u + 0x7FFFu + ((u >> 16) & 1u);
    return (u16)(r >> 16);
}
__device__ __forceinline__ float lo2f(u32 u) { return __builtin_bit_cast(float, u << 16); }
__device__ __forceinline__ float hi2f(u32 u) { return __builtin_bit_cast(float, u & 0xFFFF0000u); }

// ---------------- wave-uniform self-detection ----------------
__device__ __forceinline__ void self_detect(const int* ei, const u32* xw, int& is64, int& isbf) {
    int lane = threadIdx.x & 63;
    int v = ei ? ei[2 * lane + 1] : 0;
    unsigned long long b1 = __ballot(v == 0);
    u32 w = xw ? xw[lane] : 0;
    u32 e = (w >> 7) & 0xFF;
    int plaus = (e == 0) || (e >= 90 && e <= 140);
    unsigned long long b2 = __ballot(plaus);
    is64 = (b1 == ~0ULL) ? 1 : 0;
    isbf = (b2 == ~0ULL) ? 1 : 0;
}

__device__ __forceinline__ int load_id(const int* __restrict__ ei, int is64, size_t pos, int N) {
    int v = is64 ? ei[2 * pos] : ei[pos];
    unsigned u = (unsigned)v;
    if (u >= (unsigned)N) u = 0;  // clamp: never OOB
    return (int)u;
}

__device__ __forceinline__ float load_f(const void* __restrict__ p, int isbf, size_t i) {
    if (isbf) {
        u16 s = ((const u16*)p)[i];
        return __builtin_bit_cast(float, ((u32)s) << 16);
    }
    return ((const float*)p)[i];
}

// ---------------- merged front: convert_x + wprep + smalls + bucket_scatter ----------------
// (proven round-4 form)
#define CH 4096
#define CAPB 3072

__global__ __launch_bounds__(1024) void front_kernel(
    const void* __restrict__ xraw, const int* __restrict__ ei, int E, int N, int cvb,
    u32* __restrict__ xb, int* __restrict__ gcur, u32* __restrict__ csrbkt,
    const void* Wl1, const void* Wr1, const void* Wl2, const void* Wr2,
    const void* Wl3, const void* Wr3, const void* b1, const void* b2,
    const void* b3, const void* Wo, const void* bo,
    u16* __restrict__ Wcp, float* __restrict__ smalls) {
    __shared__ int lhist[1024], loff[1024], lcur[1024], gofs[1024], wsum[16];
    __shared__ u32 ebuf[CH];
    __shared__ u16 ebkt[CH];
    int blk = blockIdx.x;
    int t = threadIdx.x;

    if (blk < cvb) {
        int is64, isbf;
        self_detect(nullptr, (const u32*)xraw, is64, isbf);
        int i = blk * 1024 + t;
        int count4 = N * 16;
        if (i >= count4) return;
        if (isbf) {
            ((u32x4*)xb)[i] = ((const u32x4*)xraw)[i];
        } else {
            const floatx4* f4 = (const floatx4*)xraw;
            floatx4 f0 = f4[2 * i], f1 = f4[2 * i + 1];
            u32x4 o;
            o.x = (u32)f2b(f0.x) | ((u32)f2b(f0.y) << 16);
            o.y = (u32)f2b(f0.z) | ((u32)f2b(f0.w) << 16);
            o.z = (u32)f2b(f1.x) | ((u32)f2b(f1.y) << 16);
            o.w = (u32)f2b(f1.z) | ((u32)f2b(f1.w) << 16);
            ((u32x4*)xb)[i] = o;
        }
        return;
    }
    if (blk < cvb + 12) {
        int is64, isbf;
        self_detect(nullptr, (const u32*)xraw, is64, isbf);
        int tg = (blk - cvb) * 1024 + t;  // 0..12287
        int l = tg >> 12;
        int tt = tg & 4095;
        const void* Wl = (l == 0) ? Wl1 : (l == 1) ? Wl2 : Wl3;
        const void* Wr = (l == 0) ? Wr1 : (l == 1) ? Wr2 : Wr3;
        u16* Wout = Wcp + (size_t)l * 32768;
        int lane = tt & 63;
        int jt = (tt >> 6) & 3;
        int s = tt >> 8;
        int n = lane & 31;
        int q = lane >> 5;
        int j = jt * 32 + n;
#pragma unroll
        for (int jj = 0; jj < 8; ++jj) {
            int k = s * 16 + q * 8 + jj;
            float v = (k < 128) ? load_f(Wl, isbf, (size_t)j * 128 + k)
                                : load_f(Wr, isbf, (size_t)j * 128 + (k - 128));
            Wout[tt * 8 + jj] = f2b(v);
        }
        return;
    }
    if (blk == cvb + 12) {
        int is64, isbf;
        self_detect(nullptr, (const u32*)xraw, is64, isbf);
        if (t < 642) {
            float v;
            if (t < 128) v = load_f(b1, isbf, t);
            else if (t < 256) v = load_f(b2, isbf, t - 128);
            else if (t < 384) v = load_f(b3, isbf, t - 256);
            else if (t < 640) v = load_f(Wo, isbf, t - 384);
            else v = load_f(bo, isbf, t - 640);
            smalls[t] = v;
        }
        return;
    }

    // ---- scatter role ----
    int is64, isbf;
    self_detect(ei, nullptr, is64, isbf);
    int cbase = (blk - (cvb + 13)) * CH;
    int cn = E - cbase;
    if (cn > CH) cn = CH;
    lhist[t] = 0;
    __syncthreads();
    int mysrc[4], myb[4], mydl[4];
#pragma unroll
    for (int k = 0; k < 4; ++k) {
        int i = t + k * 1024;
        myb[k] = -1;
        if (i < cn) {
            int e = cbase + i;
            int s, d;
            if (is64) {
                s = (int)((const uint2*)ei)[(size_t)e].x;
                d = (int)((const uint2*)ei)[(size_t)E + e].x;
            } else {
                s = ei[(size_t)e];
                d = ei[(size_t)E + e];
            }
            if ((unsigned)s >= (unsigned)N) s = 0;
            if ((unsigned)d >= (unsigned)N) d = 0;
            mysrc[k] = s;
            mydl[k] = d & 255;
            myb[k] = d >> 8;
            atomicAdd(&lhist[myb[k]], 1);
        }
    }
    __syncthreads();
    int lane = t & 63, wid = t >> 6;
    int v = lhist[t];
    int inc = v;
#pragma unroll
    for (int off = 1; off < 64; off <<= 1) {
        int o = __shfl_up(inc, off);
        if (lane >= off) inc += o;
    }
    if (lane == 63) wsum[wid] = inc;
    __syncthreads();
    int wpre = 0;
    for (int w = 0; w < wid; ++w) wpre += wsum[w];
    int excl = wpre + inc - v;
    loff[t] = excl;
    lcur[t] = excl;
    if (v > 0) gofs[t] = atomicAdd(&gcur[t], v);
    __syncthreads();
#pragma unroll
    for (int k = 0; k < 4; ++k) {
        if (myb[k] >= 0) {
            int pos = atomicAdd(&lcur[myb[k]], 1);
            ebuf[pos] = (u32)mysrc[k] | ((u32)mydl[k] << 24);
            ebkt[pos] = (u16)myb[k];
        }
    }
    __syncthreads();
    // write runs: consecutive i within a bucket -> consecutive global slots
#pragma unroll
    for (int k = 0; k < 4; ++k) {
        int i = t + k * 1024;
        if (i < cn) {
            int bb = ebkt[i];
            int local = gofs[bb] + (i - loff[bb]);
            if (local < CAPB) csrbkt[(size_t)bb * CAPB + local] = ebuf[i];
        }
    }
}

// one block per bucket: counting-sort by dst-low, compact into csr via gtot cursor
// 512 threads: halves the serial per-thread pass length during this
// low-block-count (391 blocks) dispatch. Scan phases guarded to t<256.
__global__ __launch_bounds__(512) void csr_build_kernel(
    const u32* __restrict__ csrbkt, const int* __restrict__ gcur,
    int N, int* __restrict__ gtot,
    int* __restrict__ offs, int* __restrict__ cnt,
    int* __restrict__ csr) {
    __shared__ int lh[256], lcur[256], wsum[4];
    __shared__ int sbase;
    __shared__ u32 sbuf[CAPB];
    int t = threadIdx.x;  // 512
    int b = blockIdx.x;
    int cb = gcur[b];
    if (cb > CAPB) cb = CAPB;
    const u32* bsrc = csrbkt + (size_t)b * CAPB;
    int d0 = b << 8;
    if (t < 256) lh[t] = 0;
    __syncthreads();
    for (int i = t; i < cb; i += 512) atomicAdd(&lh[bsrc[i] >> 24], 1);
    __syncthreads();
    int lane = t & 63, wid = t >> 6;
    if (t < 256) {
        int v = lh[t];
        int inc = v;
#pragma unroll
        for (int off = 1; off < 64; off <<= 1) {
            int o = __shfl_up(inc, off);
            if (lane >= off) inc += o;
        }
        if (lane == 63) wsum[wid] = inc;
    }
    __syncthreads();
    if (t < 256) {
        int v = lh[t];
        int inc = v;
#pragma unroll
        for (int off = 1; off < 64; off <<= 1) {
            int o = __shfl_up(inc, off);
            if (lane >= off) inc += o;
        }
        int wpre = 0;
        for (int w = 0; w < wid; ++w) wpre += wsum[w];
        int excl = wpre + inc - v;
        lcur[t] = excl;
        int d = d0 + t;
        if (d < N) {
            // offs written after sbase known; stash excl in lh (reuse)
            lh[t] = excl;
            cnt[d] = v;
        }
    }
    if (t == 0) sbase = atomicAdd(gtot, cb);
    __syncthreads();
    int base = sbase;
    if (t < 256) {
        int d = d0 + t;
        if (d < N) offs[d] = base + lh[t];
    }
    for (int i = t; i < cb; i += 512) {
        u32 e = bsrc[i];
        int pos = atomicAdd(&lcur[e >> 24], 1);
        sbuf[pos] = e & 0xFFFFFFu;
    }
    __syncthreads();
    for (int i = t; i < cb; i += 512) csr[base + i] = (int)sbuf[i];
}

// ---------------- aggregation (round-0 proven form, best measured 42.3 µs) ----------------
// XCD-affine tiling, 4 nodes/wave processed serially, 8-deep unrolled gather.
// At its practical roofline: 3 distinct structures converge at ~2.75 TB/s
// (random-256B HBM efficiency limit); fetch 89.5 MB beats the naive
// distinct-row floor via L2 retention. DO NOT TOUCH.

__global__ void agg_kernel(const u32* __restrict__ F2, const int* __restrict__ offs,
                           const int* __restrict__ cnt, const int* __restrict__ csr,
                           u32* __restrict__ Aout, int N, int tstride) {
    int sub = blockIdx.x / tstride;
    int tile = blockIdx.x % tstride;
    int w = threadIdx.x >> 6;
    int lane = threadIdx.x & 63;
    int nd0 = tile * 128 + sub * 16 + w * 4;
    if (nd0 >= N) return;
    int nd1 = nd0 + 4 < N ? nd0 + 4 : N;
    for (int nd = nd0; nd < nd1; ++nd) {
        int start = offs[nd];
        int num = cnt[nd];
        float a0 = 0.f, a1 = 0.f;
        int i = 0;
        for (; i + 8 <= num; i += 8) {
            int s0 = csr[start + i + 0], s1 = csr[start + i + 1];
            int s2 = csr[start + i + 2], s3 = csr[start + i + 3];
            int s4 = csr[start + i + 4], s5 = csr[start + i + 5];
            int s6 = csr[start + i + 6], s7 = csr[start + i + 7];
            u32 u0 = F2[(size_t)s0 * 64 + lane];
            u32 u1 = F2[(size_t)s1 * 64 + lane];
            u32 u2 = F2[(size_t)s2 * 64 + lane];
            u32 u3 = F2[(size_t)s3 * 64 + lane];
            u32 u4 = F2[(size_t)s4 * 64 + lane];
            u32 u5 = F2[(size_t)s5 * 64 + lane];
            u32 u6 = F2[(size_t)s6 * 64 + lane];
            u32 u7 = F2[(size_t)s7 * 64 + lane];
            a0 += lo2f(u0) + lo2f(u1) + lo2f(u2) + lo2f(u3) +
                  lo2f(u4) + lo2f(u5) + lo2f(u6) + lo2f(u7);
            a1 += hi2f(u0) + hi2f(u1) + hi2f(u2) + hi2f(u3) +
                  hi2f(u4) + hi2f(u5) + hi2f(u6) + hi2f(u7);
        }
        for (; i + 4 <= num; i += 4) {
            int s0 = csr[start + i + 0], s1 = csr[start + i + 1];
            int s2 = csr[start + i + 2], s3 = csr[start + i + 3];
            u32 u0 = F2[(size_t)s0 * 64 + lane];
            u32 u1 = F2[(size_t)s1 * 64 + lane];
            u32 u2 = F2[(size_t)s2 * 64 + lane];
            u32 u3 = F2[(size_t)s3 * 64 + lane];
            a0 += lo2f(u0) + lo2f(u1) + lo2f(u2) + lo2f(u3);
            a1 += hi2f(u0) + hi2f(u1) + hi2f(u2) + hi2f(u3);
        }
        for (; i < num; ++i) {
            u32 u = F2[(size_t)csr[start + i] * 64 + lane];
            a0 += lo2f(u);
            a1 += hi2f(u);
        }
        float sc = 1.0f / (float)(num > 1 ? num : 1);
        a0 *= sc;
        a1 *= sc;
        Aout[(size_t)nd * 64 + lane] = (u32)f2b(a0) | ((u32)f2b(a1) << 16);
    }
}

// ---------------- dual-GEMM: F = act(concat(agg,F) @ Wc + b), IN-PLACE ----------------
// __launch_bounds__(256, 4): cap VGPR at 128 (64 acc + working set) to force
// 16 waves/CU; without it the unrolled 80-load body inflates VGPR past 168
// and drops to 8 waves/CU, leaving the kernel latency-bound on A/B loads.
__global__ __launch_bounds__(256, 4) void gemm_kernel(
    const u32* __restrict__ aggb, u32* Fio,
    const u16* __restrict__ Wcp, const float* __restrict__ biasf,
    int N, int relu, const float* __restrict__ headw,
    const u32* __restrict__ xw, void* __restrict__ outp) {
    int tid = threadIdx.x;
    int w = tid >> 6;
    int lane = tid & 63;
    int nbase = blockIdx.x * 128;
    int n = lane & 31;
    int q = lane >> 5;
    int rowl = w * 32 + n;
    int node = nbase + rowl;
    int nodeC = (node < N) ? node : (N - 1);
    const u32* aRow = aggb + (size_t)nodeC * 64 + q * 4;
    const u32* fRow = Fio + (size_t)nodeC * 64 + q * 4;

    floatx16 acc0 = 0.0f, acc1 = 0.0f, acc2 = 0.0f, acc3 = 0.0f;

#pragma unroll
    for (int s = 0; s < 16; ++s) {
        const u32* ap = (s < 8) ? (aRow + (size_t)s * 8) : (fRow + (size_t)(s - 8) * 8);
        bf16x8 a = *reinterpret_cast<const bf16x8*>(ap);
        const u16* bp = Wcp + (size_t)((s * 4) * 64 + lane) * 8;
        bf16x8 b0 = *reinterpret_cast<const bf16x8*>(bp);
        bf16x8 b1 = *reinterpret_cast<const bf16x8*>(bp + 64 * 8);
        bf16x8 b2 = *reinterpret_cast<const bf16x8*>(bp + 2 * 64 * 8);
        bf16x8 b3 = *reinterpret_cast<const bf16x8*>(bp + 3 * 64 * 8);
        acc0 = __builtin_amdgcn_mfma_f32_32x32x16_bf16(a, b0, acc0, 0, 0, 0);
        acc1 = __builtin_amdgcn_mfma_f32_32x32x16_bf16(a, b1, acc1, 0, 0, 0);
        acc2 = __builtin_amdgcn_mfma_f32_32x32x16_bf16(a, b2, acc2, 0, 0, 0);
        acc3 = __builtin_amdgcn_mfma_f32_32x32x16_bf16(a, b3, acc3, 0, 0, 0);
    }

    int mbase = nbase + w * 32;
    floatx16 accs[4] = {acc0, acc1, acc2, acc3};
    // C/D: col=lane&31, row=(r&3)+8*(r>>2)+4*(lane>>5)  [verified m74/m101]

    if (outp == nullptr) {
#pragma unroll
        for (int jt = 0; jt < 4; ++jt) {
            int j0 = jt * 32 + n;
            float bf = biasf[j0];
#pragma unroll
            for (int r = 0; r < 16; ++r) {
                int row = (r & 3) + 8 * (r >> 2) + 4 * q;
                int nodeS = mbase + row;
                if (nodeS < N) {
                    float v = accs[jt][r] + bf;
                    if (relu) v = fmaxf(v, 0.0f);
                    u16* dst16 = (u16*)&Fio[(size_t)nodeS * 64];
                    dst16[j0] = f2b(v);
                }
            }
        }
    } else {
        // fused head: out[node] = (h·Wo0 + bo0, h·Wo1 + bo1); h = acc + bl3
        int is64, isbf;
        self_detect(nullptr, xw, is64, isbf);  // full wave active here
#pragma unroll
        for (int r = 0; r < 16; ++r) {
            float p0 = 0.f, p1 = 0.f;
#pragma unroll
            for (int jt = 0; jt < 4; ++jt) {
                int j = jt * 32 + n;
                float v = accs[jt][r] + biasf[j];
                p0 += v * headw[j];
                p1 += v * headw[128 + j];
            }
#pragma unroll
            for (int off = 16; off > 0; off >>= 1) {
                p0 += __shfl_xor(p0, off);
                p1 += __shfl_xor(p1, off);
            }
            if (n == 0) {
                int row = (r & 3) + 8 * (r >> 2) + 4 * q;
                int nodeS = mbase + row;
                if (nodeS < N) {
                    float o0 = p0 + headw[256];  // bo0
                    float o1 = p1 + headw[257];  // bo1
                    if (isbf)
                        ((u32*)outp)[nodeS] = (u32)f2b(o0) | ((u32)f2b(o1) << 16);
                    else
                        ((float2*)outp)[nodeS] = make_float2(o0, o1);
                }
            }
        }
    }
}

extern "C" void kernel_launch(void* const* d_in, const int* in_sizes, int n_in,
                              void* d_out, int out_size, void* d_ws, size_t ws_size,
                              hipStream_t stream) {
    const int N = in_sizes[0] / 128;
    const int E = in_sizes[1] / 2;

    const void* x = d_in[0];
    const int* ei = (const int*)d_in[1];
    const void* Wl[3] = {d_in[2], d_in[5], d_in[8]};
    const void* bl[3] = {d_in[3], d_in[6], d_in[9]};
    const void* Wr[3] = {d_in[4], d_in[7], d_in[10]};
    const void* Wo = d_in[11];
    const void* bo = d_in[12];

    // workspace bump allocator (256B aligned)
    char* p = (char*)d_ws;
    auto alloc = [&](size_t bytes) -> char* {
        char* r = p;
        p += (bytes + 255) & ~(size_t)255;
        return r;
    };
    int* offs = (int*)alloc((size_t)N * 4);
    int* cnt = (int*)alloc((size_t)N * 4);
    float* smalls = (float*)alloc(642 * 4);
    int* gcur = (int*)alloc(1025 * 4);  // [1024] = gtot
    int* csr = (int*)alloc(((size_t)E + CAPB + 64) * 4);  // over-alloc: padded reads safe
    u16* Wcp = (u16*)alloc((size_t)3 * 4096 * 8 * 2);
    u32* xb = (u32*)alloc((size_t)(N + 1) * 64 * 4);
    u32* aggb = (u32*)alloc((size_t)N * 64 * 4);  // agg features; aliased as csrbkt during build
    u32* csrbkt = aggb;                            // dead until layers start
    int* gtot = gcur + 1024;
    (void)ws_size;

    const int NB = (N + 255) / 256;          // buckets
    const int cvb = (N * 16 + 1023) / 1024;  // convert blocks (1024 thr)
    const int sb = (E + CH - 1) / CH;        // scatter blocks
    const int gb = (N + 127) / 128;          // gemm blocks (tiles)
    const int tstride = (gb + 7) & ~7;       // tile stride, mult of 8 (XCD affinity)
    const int ab = 8 * tstride;              // agg blocks: 8 sub-blocks x tstride tiles

    hipMemsetAsync(gcur, 0, 1025 * 4, stream);
    front_kernel<<<cvb + 13 + sb, 1024, 0, stream>>>(
        x, ei, E, N, cvb, xb, gcur, csrbkt,
        Wl[0], Wr[0], Wl[1], Wr[1], Wl[2], Wr[2],
        bl[0], bl[1], bl[2], Wo, bo, Wcp, smalls);
    csr_build_kernel<<<NB, 512, 0, stream>>>(csrbkt, gcur, N, gtot, offs, cnt, csr);

    // layer 1
    agg_kernel<<<ab, 256, 0, stream>>>(xb, offs, cnt, csr, aggb, N, tstride);
    gemm_kernel<<<gb, 256, 0, stream>>>(aggb, xb, Wcp, smalls, N, 1, nullptr, nullptr, nullptr);
    // layer 2
    agg_kernel<<<ab, 256, 0, stream>>>(xb, offs, cnt, csr, aggb, N, tstride);
    gemm_kernel<<<gb, 256, 0, stream>>>(aggb, xb, Wcp + 32768, smalls + 128, N, 1, nullptr, nullptr, nullptr);
    // layer 3 + fused head
    agg_kernel<<<ab, 256, 0, stream>>>(xb, offs, cnt, csr, aggb, N, tstride);
    gemm_kernel<<<gb, 256, 0, stream>>>(aggb, xb, Wcp + 65536, smalls + 256, N, 0,
                                        smalls + 384, (const u32*)x, d_out);
}

// Round 6
// 330.328 us; speedup vs baseline: 1.1822x; 1.0266x over previous
//
#include <hip/hip_runtime.h>
#include <stdint.h>

typedef unsigned int u32;
typedef unsigned short u16;
typedef __bf16 bf16x8 __attribute__((ext_vector_type(8)));
typedef float floatx16 __attribute__((ext_vector_type(16)));
typedef u32 u32x4 __attribute__((ext_vector_type(4)));
typedef float floatx4 __attribute__((ext_vector_type(4)));

__device__ __forceinline__ u16 f2b(float f) {
    u32 u = __builtin_bit_cast(u32, f);
    u32 r = u + 0x7FFFu + ((u >> 16) & 1u);
    return (u16)(r >> 16);
}
__device__ __forceinline__ float lo2f(u32 u) { return __builtin_bit_cast(float, u << 16); }
__device__ __forceinline__ float hi2f(u32 u) { return __builtin_bit_cast(float, u & 0xFFFF0000u); }

// ---------------- wave-uniform self-detection ----------------
__device__ __forceinline__ void self_detect(const int* ei, const u32* xw, int& is64, int& isbf) {
    int lane = threadIdx.x & 63;
    int v = ei ? ei[2 * lane + 1] : 0;
    unsigned long long b1 = __ballot(v == 0);
    u32 w = xw ? xw[lane] : 0;
    u32 e = (w >> 7) & 0xFF;
    int plaus = (e == 0) || (e >= 90 && e <= 140);
    unsigned long long b2 = __ballot(plaus);
    is64 = (b1 == ~0ULL) ? 1 : 0;
    isbf = (b2 == ~0ULL) ? 1 : 0;
}

__device__ __forceinline__ int load_id(const int* __restrict__ ei, int is64, size_t pos, int N) {
    int v = is64 ? ei[2 * pos] : ei[pos];
    unsigned u = (unsigned)v;
    if (u >= (unsigned)N) u = 0;  // clamp: never OOB
    return (int)u;
}

__device__ __forceinline__ float load_f(const void* __restrict__ p, int isbf, size_t i) {
    if (isbf) {
        u16 s = ((const u16*)p)[i];
        return __builtin_bit_cast(float, ((u32)s) << 16);
    }
    return ((const float*)p)[i];
}

// ---------------- merged front: convert_x + wprep + smalls + bucket_scatter ----------------
// (proven round-4/5 form — DO NOT TOUCH)
#define CH 4096
#define CAPB 3072

__global__ __launch_bounds__(1024) void front_kernel(
    const void* __restrict__ xraw, const int* __restrict__ ei, int E, int N, int cvb,
    u32* __restrict__ xb, int* __restrict__ gcur, u32* __restrict__ csrbkt,
    const void* Wl1, const void* Wr1, const void* Wl2, const void* Wr2,
    const void* Wl3, const void* Wr3, const void* b1, const void* b2,
    const void* b3, const void* Wo, const void* bo,
    u16* __restrict__ Wcp, float* __restrict__ smalls) {
    __shared__ int lhist[1024], loff[1024], lcur[1024], gofs[1024], wsum[16];
    __shared__ u32 ebuf[CH];
    __shared__ u16 ebkt[CH];
    int blk = blockIdx.x;
    int t = threadIdx.x;

    if (blk < cvb) {
        int is64, isbf;
        self_detect(nullptr, (const u32*)xraw, is64, isbf);
        int i = blk * 1024 + t;
        int count4 = N * 16;
        if (i >= count4) return;
        if (isbf) {
            ((u32x4*)xb)[i] = ((const u32x4*)xraw)[i];
        } else {
            const floatx4* f4 = (const floatx4*)xraw;
            floatx4 f0 = f4[2 * i], f1 = f4[2 * i + 1];
            u32x4 o;
            o.x = (u32)f2b(f0.x) | ((u32)f2b(f0.y) << 16);
            o.y = (u32)f2b(f0.z) | ((u32)f2b(f0.w) << 16);
            o.z = (u32)f2b(f1.x) | ((u32)f2b(f1.y) << 16);
            o.w = (u32)f2b(f1.z) | ((u32)f2b(f1.w) << 16);
            ((u32x4*)xb)[i] = o;
        }
        return;
    }
    if (blk < cvb + 12) {
        int is64, isbf;
        self_detect(nullptr, (const u32*)xraw, is64, isbf);
        int tg = (blk - cvb) * 1024 + t;  // 0..12287
        int l = tg >> 12;
        int tt = tg & 4095;
        const void* Wl = (l == 0) ? Wl1 : (l == 1) ? Wl2 : Wl3;
        const void* Wr = (l == 0) ? Wr1 : (l == 1) ? Wr2 : Wr3;
        u16* Wout = Wcp + (size_t)l * 32768;
        int lane = tt & 63;
        int jt = (tt >> 6) & 3;
        int s = tt >> 8;
        int n = lane & 31;
        int q = lane >> 5;
        int j = jt * 32 + n;
#pragma unroll
        for (int jj = 0; jj < 8; ++jj) {
            int k = s * 16 + q * 8 + jj;
            float v = (k < 128) ? load_f(Wl, isbf, (size_t)j * 128 + k)
                                : load_f(Wr, isbf, (size_t)j * 128 + (k - 128));
            Wout[tt * 8 + jj] = f2b(v);
        }
        return;
    }
    if (blk == cvb + 12) {
        int is64, isbf;
        self_detect(nullptr, (const u32*)xraw, is64, isbf);
        if (t < 642) {
            float v;
            if (t < 128) v = load_f(b1, isbf, t);
            else if (t < 256) v = load_f(b2, isbf, t - 128);
            else if (t < 384) v = load_f(b3, isbf, t - 256);
            else if (t < 640) v = load_f(Wo, isbf, t - 384);
            else v = load_f(bo, isbf, t - 640);
            smalls[t] = v;
        }
        return;
    }

    // ---- scatter role ----
    int is64, isbf;
    self_detect(ei, nullptr, is64, isbf);
    int cbase = (blk - (cvb + 13)) * CH;
    int cn = E - cbase;
    if (cn > CH) cn = CH;
    lhist[t] = 0;
    __syncthreads();
    int mysrc[4], myb[4], mydl[4];
#pragma unroll
    for (int k = 0; k < 4; ++k) {
        int i = t + k * 1024;
        myb[k] = -1;
        if (i < cn) {
            int e = cbase + i;
            int s, d;
            if (is64) {
                s = (int)((const uint2*)ei)[(size_t)e].x;
                d = (int)((const uint2*)ei)[(size_t)E + e].x;
            } else {
                s = ei[(size_t)e];
                d = ei[(size_t)E + e];
            }
            if ((unsigned)s >= (unsigned)N) s = 0;
            if ((unsigned)d >= (unsigned)N) d = 0;
            mysrc[k] = s;
            mydl[k] = d & 255;
            myb[k] = d >> 8;
            atomicAdd(&lhist[myb[k]], 1);
        }
    }
    __syncthreads();
    int lane = t & 63, wid = t >> 6;
    int v = lhist[t];
    int inc = v;
#pragma unroll
    for (int off = 1; off < 64; off <<= 1) {
        int o = __shfl_up(inc, off);
        if (lane >= off) inc += o;
    }
    if (lane == 63) wsum[wid] = inc;
    __syncthreads();
    int wpre = 0;
    for (int w = 0; w < wid; ++w) wpre += wsum[w];
    int excl = wpre + inc - v;
    loff[t] = excl;
    lcur[t] = excl;
    if (v > 0) gofs[t] = atomicAdd(&gcur[t], v);
    __syncthreads();
#pragma unroll
    for (int k = 0; k < 4; ++k) {
        if (myb[k] >= 0) {
            int pos = atomicAdd(&lcur[myb[k]], 1);
            ebuf[pos] = (u32)mysrc[k] | ((u32)mydl[k] << 24);
            ebkt[pos] = (u16)myb[k];
        }
    }
    __syncthreads();
    // write runs: consecutive i within a bucket -> consecutive global slots
#pragma unroll
    for (int k = 0; k < 4; ++k) {
        int i = t + k * 1024;
        if (i < cn) {
            int bb = ebkt[i];
            int local = gofs[bb] + (i - loff[bb]);
            if (local < CAPB) csrbkt[(size_t)bb * CAPB + local] = ebuf[i];
        }
    }
}

// one block per bucket: counting-sort by dst-low, compact into csr via gtot cursor
// (proven round-5 form, 512 threads)
__global__ __launch_bounds__(512) void csr_build_kernel(
    const u32* __restrict__ csrbkt, const int* __restrict__ gcur,
    int N, int* __restrict__ gtot,
    int* __restrict__ offs, int* __restrict__ cnt,
    int* __restrict__ csr) {
    __shared__ int lh[256], lcur[256], wsum[4];
    __shared__ int sbase;
    __shared__ u32 sbuf[CAPB];
    int t = threadIdx.x;  // 512
    int b = blockIdx.x;
    int cb = gcur[b];
    if (cb > CAPB) cb = CAPB;
    const u32* bsrc = csrbkt + (size_t)b * CAPB;
    int d0 = b << 8;
    if (t < 256) lh[t] = 0;
    __syncthreads();
    for (int i = t; i < cb; i += 512) atomicAdd(&lh[bsrc[i] >> 24], 1);
    __syncthreads();
    int lane = t & 63, wid = t >> 6;
    if (t < 256) {
        int v = lh[t];
        int inc = v;
#pragma unroll
        for (int off = 1; off < 64; off <<= 1) {
            int o = __shfl_up(inc, off);
            if (lane >= off) inc += o;
        }
        if (lane == 63) wsum[wid] = inc;
    }
    __syncthreads();
    if (t < 256) {
        int v = lh[t];
        int inc = v;
#pragma unroll
        for (int off = 1; off < 64; off <<= 1) {
            int o = __shfl_up(inc, off);
            if (lane >= off) inc += o;
        }
        int wpre = 0;
        for (int w = 0; w < wid; ++w) wpre += wsum[w];
        int excl = wpre + inc - v;
        lcur[t] = excl;
        int d = d0 + t;
        if (d < N) {
            lh[t] = excl;  // stash excl (reuse lh)
            cnt[d] = v;
        }
    }
    if (t == 0) sbase = atomicAdd(gtot, cb);
    __syncthreads();
    int base = sbase;
    if (t < 256) {
        int d = d0 + t;
        if (d < N) offs[d] = base + lh[t];
    }
    for (int i = t; i < cb; i += 512) {
        u32 e = bsrc[i];
        int pos = atomicAdd(&lcur[e >> 24], 1);
        sbuf[pos] = e & 0xFFFFFFu;
    }
    __syncthreads();
    for (int i = t; i < cb; i += 512) csr[base + i] = (int)sbuf[i];
}

// ---------------- aggregation (round-0 proven form, best measured 42.3 µs) ----------------
// At its practical roofline (~2.75 TB/s random-256B HBM). DO NOT TOUCH.

__global__ void agg_kernel(const u32* __restrict__ F2, const int* __restrict__ offs,
                           const int* __restrict__ cnt, const int* __restrict__ csr,
                           u32* __restrict__ Aout, int N, int tstride) {
    int sub = blockIdx.x / tstride;
    int tile = blockIdx.x % tstride;
    int w = threadIdx.x >> 6;
    int lane = threadIdx.x & 63;
    int nd0 = tile * 128 + sub * 16 + w * 4;
    if (nd0 >= N) return;
    int nd1 = nd0 + 4 < N ? nd0 + 4 : N;
    for (int nd = nd0; nd < nd1; ++nd) {
        int start = offs[nd];
        int num = cnt[nd];
        float a0 = 0.f, a1 = 0.f;
        int i = 0;
        for (; i + 8 <= num; i += 8) {
            int s0 = csr[start + i + 0], s1 = csr[start + i + 1];
            int s2 = csr[start + i + 2], s3 = csr[start + i + 3];
            int s4 = csr[start + i + 4], s5 = csr[start + i + 5];
            int s6 = csr[start + i + 6], s7 = csr[start + i + 7];
            u32 u0 = F2[(size_t)s0 * 64 + lane];
            u32 u1 = F2[(size_t)s1 * 64 + lane];
            u32 u2 = F2[(size_t)s2 * 64 + lane];
            u32 u3 = F2[(size_t)s3 * 64 + lane];
            u32 u4 = F2[(size_t)s4 * 64 + lane];
            u32 u5 = F2[(size_t)s5 * 64 + lane];
            u32 u6 = F2[(size_t)s6 * 64 + lane];
            u32 u7 = F2[(size_t)s7 * 64 + lane];
            a0 += lo2f(u0) + lo2f(u1) + lo2f(u2) + lo2f(u3) +
                  lo2f(u4) + lo2f(u5) + lo2f(u6) + lo2f(u7);
            a1 += hi2f(u0) + hi2f(u1) + hi2f(u2) + hi2f(u3) +
                  hi2f(u4) + hi2f(u5) + hi2f(u6) + hi2f(u7);
        }
        for (; i + 4 <= num; i += 4) {
            int s0 = csr[start + i + 0], s1 = csr[start + i + 1];
            int s2 = csr[start + i + 2], s3 = csr[start + i + 3];
            u32 u0 = F2[(size_t)s0 * 64 + lane];
            u32 u1 = F2[(size_t)s1 * 64 + lane];
            u32 u2 = F2[(size_t)s2 * 64 + lane];
            u32 u3 = F2[(size_t)s3 * 64 + lane];
            a0 += lo2f(u0) + lo2f(u1) + lo2f(u2) + lo2f(u3);
            a1 += hi2f(u0) + hi2f(u1) + hi2f(u2) + hi2f(u3);
        }
        for (; i < num; ++i) {
            u32 u = F2[(size_t)csr[start + i] * 64 + lane];
            a0 += lo2f(u);
            a1 += hi2f(u);
        }
        float sc = 1.0f / (float)(num > 1 ? num : 1);
        a0 *= sc;
        a1 *= sc;
        Aout[(size_t)nd * 64 + lane] = (u32)f2b(a0) | ((u32)f2b(a1) << 16);
    }
}

// ---------------- dual-GEMM: F = act(concat(agg,F) @ Wc + b), IN-PLACE ----------------
// Epilogue v2: wave-private LDS transpose. Old epilogue issued 64 scalar
// global_store_short per thread (12.8M 2-B stores/dispatch, 128 B committed
// per instruction). Now: f2b results -> per-wave LDS tile [32][68] u16
// (stride 136 B: 8-B aligned b64 reads, <=2-way bank conflicts), read back
// 16 B/lane, store 8x global_store_dwordx4 (full 16-B segments, 8x fewer
// VMEM stores). No __syncthreads: each wave touches only its own LDS rows
// (DS ops are in-order within a wave). LDS 17.4 KB -> thread cap (8 blk/CU)
// still binds occupancy, not LDS.
__global__ __launch_bounds__(256, 4) void gemm_kernel(
    const u32* __restrict__ aggb, u32* Fio,
    const u16* __restrict__ Wcp, const float* __restrict__ biasf,
    int N, int relu, const float* __restrict__ headw,
    const u32* __restrict__ xw, void* __restrict__ outp) {
    __shared__ u16 ldsT[4][32][68];
    int tid = threadIdx.x;
    int w = tid >> 6;
    int lane = tid & 63;
    int nbase = blockIdx.x * 128;
    int n = lane & 31;
    int q = lane >> 5;
    int rowl = w * 32 + n;
    int node = nbase + rowl;
    int nodeC = (node < N) ? node : (N - 1);
    const u32* aRow = aggb + (size_t)nodeC * 64 + q * 4;
    const u32* fRow = Fio + (size_t)nodeC * 64 + q * 4;

    floatx16 acc0 = 0.0f, acc1 = 0.0f, acc2 = 0.0f, acc3 = 0.0f;

#pragma unroll
    for (int s = 0; s < 16; ++s) {
        const u32* ap = (s < 8) ? (aRow + (size_t)s * 8) : (fRow + (size_t)(s - 8) * 8);
        bf16x8 a = *reinterpret_cast<const bf16x8*>(ap);
        const u16* bp = Wcp + (size_t)((s * 4) * 64 + lane) * 8;
        bf16x8 b0 = *reinterpret_cast<const bf16x8*>(bp);
        bf16x8 b1 = *reinterpret_cast<const bf16x8*>(bp + 64 * 8);
        bf16x8 b2 = *reinterpret_cast<const bf16x8*>(bp + 2 * 64 * 8);
        bf16x8 b3 = *reinterpret_cast<const bf16x8*>(bp + 3 * 64 * 8);
        acc0 = __builtin_amdgcn_mfma_f32_32x32x16_bf16(a, b0, acc0, 0, 0, 0);
        acc1 = __builtin_amdgcn_mfma_f32_32x32x16_bf16(a, b1, acc1, 0, 0, 0);
        acc2 = __builtin_amdgcn_mfma_f32_32x32x16_bf16(a, b2, acc2, 0, 0, 0);
        acc3 = __builtin_amdgcn_mfma_f32_32x32x16_bf16(a, b3, acc3, 0, 0, 0);
    }

    int mbase = nbase + w * 32;
    floatx16 accs[4] = {acc0, acc1, acc2, acc3};
    // C/D: col=lane&31, row=(r&3)+8*(r>>2)+4*(lane>>5)  [verified m74/m101]

    if (outp == nullptr) {
        int rowg = mbase + n;       // the row this lane stores after transpose
        int okrow = rowg < N;
#pragma unroll
        for (int h = 0; h < 2; ++h) {
            // write phase: two col-quadrants (64 cols) of this wave's 32 rows
#pragma unroll
            for (int jt2 = 0; jt2 < 2; ++jt2) {
                int jt = h * 2 + jt2;
                int j0 = jt * 32 + n;
                float bf = biasf[j0];
#pragma unroll
                for (int r = 0; r < 16; ++r) {
                    int row = (r & 3) + 8 * (r >> 2) + 4 * q;
                    float v = accs[jt][r] + bf;
                    if (relu) v = fmaxf(v, 0.0f);
                    ldsT[w][row][jt2 * 32 + n] = f2b(v);
                }
            }
            // read back + coalesced store: lane (n,q) owns row n, 16 B x4
#pragma unroll
            for (int i = 0; i < 4; ++i) {
                const u16* lp = &ldsT[w][n][q * 8 + i * 16];
                uint2 lo = *reinterpret_cast<const uint2*>(lp);
                uint2 hi = *reinterpret_cast<const uint2*>(lp + 4);
                if (okrow) {
                    u32x4 o;
                    o.x = lo.x; o.y = lo.y; o.z = hi.x; o.w = hi.y;
                    *reinterpret_cast<u32x4*>(&Fio[(size_t)rowg * 64 + h * 32 + q * 4 + i * 8]) = o;
                }
            }
        }
    } else {
        // fused head: out[node] = (h·Wo0 + bo0, h·Wo1 + bo1); h = acc + bl3
        int is64, isbf;
        self_detect(nullptr, xw, is64, isbf);  // full wave active here
#pragma unroll
        for (int r = 0; r < 16; ++r) {
            float p0 = 0.f, p1 = 0.f;
#pragma unroll
            for (int jt = 0; jt < 4; ++jt) {
                int j = jt * 32 + n;
                float v = accs[jt][r] + biasf[j];
                p0 += v * headw[j];
                p1 += v * headw[128 + j];
            }
#pragma unroll
            for (int off = 16; off > 0; off >>= 1) {
                p0 += __shfl_xor(p0, off);
                p1 += __shfl_xor(p1, off);
            }
            if (n == 0) {
                int row = (r & 3) + 8 * (r >> 2) + 4 * q;
                int nodeS = mbase + row;
                if (nodeS < N) {
                    float o0 = p0 + headw[256];  // bo0
                    float o1 = p1 + headw[257];  // bo1
                    if (isbf)
                        ((u32*)outp)[nodeS] = (u32)f2b(o0) | ((u32)f2b(o1) << 16);
                    else
                        ((float2*)outp)[nodeS] = make_float2(o0, o1);
                }
            }
        }
    }
}

extern "C" void kernel_launch(void* const* d_in, const int* in_sizes, int n_in,
                              void* d_out, int out_size, void* d_ws, size_t ws_size,
                              hipStream_t stream) {
    const int N = in_sizes[0] / 128;
    const int E = in_sizes[1] / 2;

    const void* x = d_in[0];
    const int* ei = (const int*)d_in[1];
    const void* Wl[3] = {d_in[2], d_in[5], d_in[8]};
    const void* bl[3] = {d_in[3], d_in[6], d_in[9]};
    const void* Wr[3] = {d_in[4], d_in[7], d_in[10]};
    const void* Wo = d_in[11];
    const void* bo = d_in[12];

    // workspace bump allocator (256B aligned)
    char* p = (char*)d_ws;
    auto alloc = [&](size_t bytes) -> char* {
        char* r = p;
        p += (bytes + 255) & ~(size_t)255;
        return r;
    };
    int* offs = (int*)alloc((size_t)N * 4);
    int* cnt = (int*)alloc((size_t)N * 4);
    float* smalls = (float*)alloc(642 * 4);
    int* gcur = (int*)alloc(1025 * 4);  // [1024] = gtot
    int* csr = (int*)alloc(((size_t)E + CAPB + 64) * 4);  // over-alloc: padded reads safe
    u16* Wcp = (u16*)alloc((size_t)3 * 4096 * 8 * 2);
    u32* xb = (u32*)alloc((size_t)(N + 1) * 64 * 4);
    u32* aggb = (u32*)alloc((size_t)N * 64 * 4);  // agg features; aliased as csrbkt during build
    u32* csrbkt = aggb;                            // dead until layers start
    int* gtot = gcur + 1024;
    (void)ws_size;

    const int NB = (N + 255) / 256;          // buckets
    const int cvb = (N * 16 + 1023) / 1024;  // convert blocks (1024 thr)
    const int sb = (E + CH - 1) / CH;        // scatter blocks
    const int gb = (N + 127) / 128;          // gemm blocks (tiles)
    const int tstride = (gb + 7) & ~7;       // tile stride, mult of 8 (XCD affinity)
    const int ab = 8 * tstride;              // agg blocks: 8 sub-blocks x tstride tiles

    hipMemsetAsync(gcur, 0, 1025 * 4, stream);
    front_kernel<<<cvb + 13 + sb, 1024, 0, stream>>>(
        x, ei, E, N, cvb, xb, gcur, csrbkt,
        Wl[0], Wr[0], Wl[1], Wr[1], Wl[2], Wr[2],
        bl[0], bl[1], bl[2], Wo, bo, Wcp, smalls);
    csr_build_kernel<<<NB, 512, 0, stream>>>(csrbkt, gcur, N, gtot, offs, cnt, csr);

    // layer 1
    agg_kernel<<<ab, 256, 0, stream>>>(xb, offs, cnt, csr, aggb, N, tstride);
    gemm_kernel<<<gb, 256, 0, stream>>>(aggb, xb, Wcp, smalls, N, 1, nullptr, nullptr, nullptr);
    // layer 2
    agg_kernel<<<ab, 256, 0, stream>>>(xb, offs, cnt, csr, aggb, N, tstride);
    gemm_kernel<<<gb, 256, 0, stream>>>(aggb, xb, Wcp + 32768, smalls + 128, N, 1, nullptr, nullptr, nullptr);
    // layer 3 + fused head
    agg_kernel<<<ab, 256, 0, stream>>>(xb, offs, cnt, csr, aggb, N, tstride);
    gemm_kernel<<<gb, 256, 0, stream>>>(aggb, xb, Wcp + 65536, smalls + 256, N, 0,
                                        smalls + 384, (const u32*)x, d_out);
}